// Round 5
// baseline (517.745 us; speedup 1.0000x reference)
//
#include <hip/hip_runtime.h>
#include <hip/hip_fp16.h>
#include <math.h>

#define EMB_DIM 256
#define NUM_EMB 2048
#define N_ROWS  65536            // 64*32*32
#define N_ELEM  16777216         // N_ROWS * EMB_DIM
#define EPS_GAP 8e-3f            // ~10 sigma of 1-pass ordering error

// ---- workspace layout (in 4-byte elements) ----
#define IDX_OFF    0             // int[65536]
#define XSQ_OFF    65536         // float[65536]
#define ESQ_OFF    131072        // float[2048]  exact ||e||^2 (fallback)
#define ESQH_OFF   133120        // float[2048]  ||eh||^2 (fp16-rounded, main)
#define HIST_OFF   135168        // int[2048]
#define BKT_OFF    137216        // float[256]
#define CNT_OFF    137472        // int[1]
#define FLG_OFF    137473        // int[65536]
#define CBT_OFF    262144        // float[2048][256]  (transposed codebook)
#define CBTH_OFF   786432        // f16 [2048][256] hi plane (1 MB)

typedef __attribute__((ext_vector_type(8))) _Float16 half8;
typedef __attribute__((ext_vector_type(4))) float f32x4;
typedef unsigned int u32;

__device__ __forceinline__ void gl_lds16(const void* g, void* l) {
    __builtin_amdgcn_global_load_lds(
        (const __attribute__((address_space(1))) u32*)g,
        (__attribute__((address_space(3))) u32*)l, 16, 0, 0);
}

// ---------- prep: exact ||e||^2 (fallback) + ||eh||^2 (main, fp16-rounded) ----------
__global__ __launch_bounds__(256) void esq_k(const float* __restrict__ cb,
                                             float* __restrict__ esq,
                                             float* __restrict__ esqh) {
    int e = blockIdx.x * 256 + threadIdx.x;
    float s0 = 0.f, s1 = 0.f, s2 = 0.f, s3 = 0.f;
    float h0 = 0.f, h1 = 0.f, h2 = 0.f, h3 = 0.f;
    for (int d = 0; d < EMB_DIM; d += 4) {
        float c0 = cb[(d + 0) * NUM_EMB + e];
        float c1 = cb[(d + 1) * NUM_EMB + e];
        float c2 = cb[(d + 2) * NUM_EMB + e];
        float c3 = cb[(d + 3) * NUM_EMB + e];
        s0 = fmaf(c0, c0, s0); s1 = fmaf(c1, c1, s1);
        s2 = fmaf(c2, c2, s2); s3 = fmaf(c3, c3, s3);
        float q0 = __half2float(__float2half(c0));
        float q1 = __half2float(__float2half(c1));
        float q2 = __half2float(__float2half(c2));
        float q3 = __half2float(__float2half(c3));
        h0 = fmaf(q0, q0, h0); h1 = fmaf(q1, q1, h1);
        h2 = fmaf(q2, q2, h2); h3 = fmaf(q3, q3, h3);
    }
    esq[e]  = (s0 + s1) + (s2 + s3);
    esqh[e] = (h0 + h1) + (h2 + h3);
}

// ---------- prep: transpose codebook to [2048][256] fp32 + fp16 hi plane ----------
__global__ __launch_bounds__(256) void prep_cbt(const float* __restrict__ cb,
                                                float* __restrict__ cbT,
                                                __half* __restrict__ cbTh) {
    __shared__ float lt[64][65];
    int t = threadIdx.x;
    int et = (blockIdx.x & 31) * 64;   // e-tile base
    int dt = (blockIdx.x >> 5) * 64;   // d-tile base
    #pragma unroll
    for (int p = 0; p < 4; ++p) {
        int d  = p * 16 + (t >> 4);
        int e4 = (t & 15) * 4;
        const float4 v = *(const float4*)&cb[(dt + d) * NUM_EMB + et + e4];
        lt[d][e4] = v.x; lt[d][e4 + 1] = v.y; lt[d][e4 + 2] = v.z; lt[d][e4 + 3] = v.w;
    }
    __syncthreads();
    #pragma unroll
    for (int p = 0; p < 4; ++p) {
        int e  = p * 16 + (t >> 4);
        int d4 = (t & 15) * 4;
        float a[4] = {lt[d4][e], lt[d4 + 1][e], lt[d4 + 2][e], lt[d4 + 3][e]};
        *(float4*)&cbT[(et + e) * EMB_DIM + dt + d4] = make_float4(a[0], a[1], a[2], a[3]);
        unsigned short hb[4];
        #pragma unroll
        for (int i = 0; i < 4; ++i)
            hb[i] = __half_as_ushort(__float2half(a[i]));
        *(ushort4*)&cbTh[(et + e) * EMB_DIM + dt + d4] = make_ushort4(hb[0], hb[1], hb[2], hb[3]);
    }
}

// ---------- prep: x -> fp16 hi plane + ||x||^2 (lo plane no longer needed) ----------
__global__ __launch_bounds__(256) void prep_x(const float* __restrict__ x,
                                              __half* __restrict__ xh,
                                              float* __restrict__ xsq) {
    int t = threadIdx.x;
    int row = blockIdx.x * 4 + (t >> 6);
    int c = (t & 63) * 4;
    const float4 v = *(const float4*)&x[row * EMB_DIM + c];
    float a[4] = {v.x, v.y, v.z, v.w};
    unsigned short hb[4];
    float s = 0.f;
    #pragma unroll
    for (int i = 0; i < 4; ++i) {
        hb[i] = __half_as_ushort(__float2half(a[i]));
        s = fmaf(a[i], a[i], s);
    }
    *(ushort4*)&xh[row * EMB_DIM + c] = make_ushort4(hb[0], hb[1], hb[2], hb[3]);
    #pragma unroll
    for (int o = 32; o > 0; o >>= 1) s += __shfl_down(s, o, 64);
    if ((t & 63) == 0) xsq[row] = s;
}

// ---------- main: 1-pass MFMA score + per-row argmin ----------
// Block = 64 rows, 4 waves; wave tile 64 rows x 128 cols (f=4,g=8); n-tile 512.
// Double-buffered depth-1 counted-vmcnt pipeline: per step,
//   STAGE(s+1); vmcnt(9); s_barrier; ds_read frags; lgkmcnt(0); s_barrier; MFMA.
// No vmcnt(0) drain in loop (only final step). Cover = one MFMA phase (~1240 cyc/SIMD).
// score v = ||eh||^2 - 2*(xh . eh); ordering error ~8e-4 pairwise, EPS_GAP = 8e-3.
#define BUFH 18432   // halfs per LDS buffer: A 2048 + B 16384  (36 KB)
__global__ __launch_bounds__(256, 2) void argmin_mfma(
    const __half* __restrict__ xh_, const __half* __restrict__ cbh_,
    const float* __restrict__ esqh,
    int* __restrict__ idx_out, int* __restrict__ cnt, int* __restrict__ flg) {

    __shared__ _Float16 ldsbuf[2 * BUFH];          // 72 KB -> 2 blocks/CU
    _Float16* lds = ldsbuf;

    const _Float16* xh  = (const _Float16*)xh_;
    const _Float16* cbh = (const _Float16*)cbh_;

    const int t = threadIdx.x;
    const int w = t >> 6, L = t & 63;
    const int wn = w * 128;                        // wave's column base within n-tile
    const int lm = L & 15, lq = L >> 4;
    const int ph = (lm >> 1) & 3;                  // frag-read XOR swizzle phase
    const int rowbase = blockIdx.x * 64;

    // staging geometry: each gl_lds16 line stages 16 rows per wave (64 rows across 4 waves)
    const int srow = L >> 2;                       // row within 16-row group
    const int sq   = (L & 3) ^ ((L >> 3) & 3);     // swizzled source chunk (x8 f16)

    const _Float16* pa  = xh + (size_t)(rowbase + w * 16 + srow) * EMB_DIM + sq * 8;
    const _Float16* pb0 = cbh + (size_t)(w * 16 + srow) * EMB_DIM + sq * 8;
    const int oA = (w * 16) * 32;                  // A region [64][32] at +0
    const int oB = 2048 + (w * 16) * 32;           // B region [512][32] at +2048

    float best[16], b2[16];
    int   bi[16];
    #pragma unroll
    for (int s = 0; s < 16; ++s) { best[s] = 3.4e38f; b2[s] = 3.4e38f; bi[s] = 0; }

    // stage group gs (step = nt*8+kt) into buffer bb: 1 A line + 8 B lines = 9 loads
    #define STAGE(gs, bb) do {                                                   \
        const int nnt_ = (gs) >> 3, nkt_ = (gs) & 7;                             \
        const int ko_  = nkt_ * 32;                                              \
        const _Float16* pb_ = pb0 + ((size_t)nnt_ * 512) * EMB_DIM + ko_;        \
        gl_lds16(pa + ko_, (bb) + oA);                                           \
        gl_lds16(pb_ +   0 * EMB_DIM, (bb) + oB +     0);                        \
        gl_lds16(pb_ +  64 * EMB_DIM, (bb) + oB +  2048);                        \
        gl_lds16(pb_ + 128 * EMB_DIM, (bb) + oB +  4096);                        \
        gl_lds16(pb_ + 192 * EMB_DIM, (bb) + oB +  6144);                        \
        gl_lds16(pb_ + 256 * EMB_DIM, (bb) + oB +  8192);                        \
        gl_lds16(pb_ + 320 * EMB_DIM, (bb) + oB + 10240);                        \
        gl_lds16(pb_ + 384 * EMB_DIM, (bb) + oB + 12288);                        \
        gl_lds16(pb_ + 448 * EMB_DIM, (bb) + oB + 14336);                        \
    } while (0)

    // prologue: stage group 0 into buf 0, drain once
    STAGE(0, lds);
    asm volatile("s_waitcnt vmcnt(0)" ::: "memory");
    __builtin_amdgcn_s_barrier();
    __builtin_amdgcn_sched_barrier(0);

    for (int nt = 0; nt < 4; ++nt) {
        // per-nt esqh preload (keeps compiler waits from draining staging loads)
        float eq[8];
        #pragma unroll
        for (int g = 0; g < 8; ++g)
            eq[g] = esqh[nt * 512 + wn + g * 16 + lm];

        f32x4 acc[4][8];
        #pragma unroll
        for (int f = 0; f < 4; ++f)
            #pragma unroll
            for (int g = 0; g < 8; ++g)
                acc[f][g] = (f32x4){0.f, 0.f, 0.f, 0.f};

        for (int kt = 0; kt < 8; ++kt) {
            const int step = nt * 8 + kt;

            // issue next group into the other buffer (none at final step)
            if (step < 31)
                STAGE(step + 1, lds + ((step + 1) & 1) * BUFH);

            __builtin_amdgcn_sched_barrier(0);
            if (step < 31) {
                asm volatile("s_waitcnt vmcnt(9)" ::: "memory");  // group-step retired; step+1 in flight
            } else {
                asm volatile("s_waitcnt vmcnt(0)" ::: "memory");  // final: drain
            }
            __builtin_amdgcn_s_barrier();          // A: all waves' group-step writes visible
            __builtin_amdgcn_sched_barrier(0);

            const _Float16* sa = lds + (step & 1) * BUFH;
            const _Float16* sb = sa + 2048;

            half8 ah[4], bh[8];
            #pragma unroll
            for (int f = 0; f < 4; ++f)
                ah[f] = *(const half8*)&sa[(f * 16 + lm) * 32 + ((lq ^ ph) * 8)];
            #pragma unroll
            for (int g = 0; g < 8; ++g)
                bh[g] = *(const half8*)&sb[(wn + g * 16 + lm) * 32 + ((lq ^ ph) * 8)];

            asm volatile("s_waitcnt lgkmcnt(0)" ::: "memory");    // frag reads complete
            __builtin_amdgcn_sched_barrier(0);
            __builtin_amdgcn_s_barrier();          // B: WAR — next overwrite is now safe
            __builtin_amdgcn_sched_barrier(0);

            __builtin_amdgcn_s_setprio(1);
            #pragma unroll
            for (int f = 0; f < 4; ++f)
                #pragma unroll
                for (int g = 0; g < 8; ++g)
                    acc[f][g] = __builtin_amdgcn_mfma_f32_16x16x32_f16(ah[f], bh[g], acc[f][g], 0, 0, 0);
            __builtin_amdgcn_s_setprio(0);
        }

        // epilogue: v = esqh - 2*sim; running (best, second, index); cols ascend -> strict <
        #pragma unroll
        for (int g = 0; g < 8; ++g) {
            int col = nt * 512 + wn + g * 16 + lm;
            #pragma unroll
            for (int f = 0; f < 4; ++f)
                #pragma unroll
                for (int r = 0; r < 4; ++r) {
                    int s = f * 4 + r;
                    float v = fmaf(-2.0f, acc[f][g][r], eq[g]);
                    float bo = best[s];
                    b2[s]   = fminf(b2[s], fmaxf(bo, v));
                    best[s] = fminf(bo, v);
                    bi[s]   = (v < bo) ? col : bi[s];
                }
        }
    }
    #undef STAGE

    // block-level reduce: 64 candidates per row
    __syncthreads();
    float* smemf = (float*)ldsbuf;
    float* rd = smemf;                  // [64][64]
    int*   ri = (int*)(smemf + 4096);
    float* r2 = smemf + 8192;           // 48 KB total, fits in ldsbuf
    #pragma unroll
    for (int f = 0; f < 4; ++f)
        #pragma unroll
        for (int r = 0; r < 4; ++r) {
            int row = f * 16 + lq * 4 + r;
            int c = w * 16 + lm;
            rd[row * 64 + c] = best[f * 4 + r];
            ri[row * 64 + c] = bi[f * 4 + r];
            r2[row * 64 + c] = b2[f * 4 + r];
        }
    __syncthreads();
    if (t < 64) {
        int row = t;
        float g1 = rd[row * 64]; int gi = ri[row * 64]; float g2 = r2[row * 64];
        for (int c = 1; c < 64; ++c) {
            float d = rd[row * 64 + c]; int ic = ri[row * 64 + c]; float d2 = r2[row * 64 + c];
            if (d < g1 || (d == g1 && ic < gi)) { g2 = fminf(g1, d2); g1 = d; gi = ic; }
            else g2 = fminf(g2, d);
        }
        idx_out[rowbase + row] = gi;
        if (g2 - g1 < EPS_GAP) {       // near-tie: route to exact fp32 fallback
            int p = atomicAdd(cnt, 1);
            flg[p] = rowbase + row;
        }
    }
}

// ---------- exact fp32 re-check for flagged (near-tie) rows ----------
// Coalesced + 4-row batched: cb original [256][2048] layout, lane t owns codes
// {t, 256+t, ...}; per-thread accumulation replicates the reference-matching
// 4-partial-sum structure -> bitwise-identical candidates.
__global__ __launch_bounds__(256) void fallback_k(const float* __restrict__ x,
                                                  const float* __restrict__ cb,
                                                  const float* __restrict__ xsq,
                                                  const float* __restrict__ esq,
                                                  const int* __restrict__ cnt,
                                                  const int* __restrict__ rows,
                                                  int* __restrict__ idx) {
    __shared__ float xr[4][256];
    __shared__ float sd[4][256];
    __shared__ int   si[4][256];
    int t = threadIdx.x;
    int n = *cnt;
    for (int base = blockIdx.x * 4; base < n; base += gridDim.x * 4) {
        int rws[4];
        #pragma unroll
        for (int r = 0; r < 4; ++r) {
            int fi = base + r;
            rws[r] = rows[(fi < n) ? fi : (n - 1)];   // pad by repeating last (benign)
        }
        __syncthreads();   // WAR vs previous group's reduce
        #pragma unroll
        for (int r = 0; r < 4; ++r) xr[r][t] = x[(size_t)rws[r] * EMB_DIM + t];
        __syncthreads();

        float bd[4]; int bidx[4];
        #pragma unroll
        for (int r = 0; r < 4; ++r) { bd[r] = 3.4e38f; bidx[r] = 0x7fffffff; }

        for (int j = 0; j < 8; ++j) {
            int e = j * 256 + t;
            float s0[4], s1[4], s2[4], s3[4];
            #pragma unroll
            for (int r = 0; r < 4; ++r) { s0[r] = 0.f; s1[r] = 0.f; s2[r] = 0.f; s3[r] = 0.f; }
            for (int d = 0; d < EMB_DIM; d += 4) {
                float c0 = cb[(size_t)(d + 0) * NUM_EMB + e];
                float c1 = cb[(size_t)(d + 1) * NUM_EMB + e];
                float c2 = cb[(size_t)(d + 2) * NUM_EMB + e];
                float c3 = cb[(size_t)(d + 3) * NUM_EMB + e];
                #pragma unroll
                for (int r = 0; r < 4; ++r) {
                    const float4 xv = *(const float4*)&xr[r][d];
                    s0[r] = fmaf(xv.x, c0, s0[r]);
                    s1[r] = fmaf(xv.y, c1, s1[r]);
                    s2[r] = fmaf(xv.z, c2, s2[r]);
                    s3[r] = fmaf(xv.w, c3, s3[r]);
                }
            }
            float eqv = esq[e];
            #pragma unroll
            for (int r = 0; r < 4; ++r) {
                float sim = (s0[r] + s1[r]) + (s2[r] + s3[r]);
                float dd = (xsq[rws[r]] + eqv) - 2.0f * sim;
                if (dd < bd[r]) { bd[r] = dd; bidx[r] = e; }   // e ascends per thread
            }
        }
        #pragma unroll
        for (int r = 0; r < 4; ++r) { sd[r][t] = bd[r]; si[r][t] = bidx[r]; }
        __syncthreads();
        for (int r = 0; r < 4; ++r) {
            for (int stp = 128; stp > 0; stp >>= 1) {
                if (t < stp) {
                    if (sd[r][t + stp] < sd[r][t] ||
                        (sd[r][t + stp] == sd[r][t] && si[r][t + stp] < si[r][t])) {
                        sd[r][t] = sd[r][t + stp]; si[r][t] = si[r][t + stp];
                    }
                }
                __syncthreads();
            }
        }
        if (t == 0) {
            #pragma unroll
            for (int r = 0; r < 4; ++r) idx[rws[r]] = si[r][0];
        }
    }
}

// ---------- quantize + straight-through + loss partials + histogram ----------
__global__ __launch_bounds__(256) void quant_k(const float* __restrict__ x,
                                               const float* __restrict__ cbT,
                                               const int* __restrict__ idx,
                                               float* __restrict__ out,
                                               float* __restrict__ bkt,
                                               int* __restrict__ hist) {
    int t = threadIdx.x;
    int row = blockIdx.x * 4 + (t >> 6);
    int c = (t & 63) * 4;
    int e = idx[row];
    const float4 q  = *(const float4*)&cbT[(size_t)e * EMB_DIM + c];
    const float4 xv = *(const float4*)&x[(size_t)row * EMB_DIM + c];
    float4 o;
    o.x = xv.x + (q.x - xv.x); o.y = xv.y + (q.y - xv.y);
    o.z = xv.z + (q.z - xv.z); o.w = xv.w + (q.w - xv.w);
    *(float4*)&out[(size_t)row * EMB_DIM + c] = o;
    float dx = xv.x - q.x, dy = xv.y - q.y, dz = xv.z - q.z, dw = xv.w - q.w;
    float val = fmaf(dx, dx, 0.f);
    val = fmaf(dy, dy, val);
    val = fmaf(dz, dz, val);
    val = fmaf(dw, dw, val);
    #pragma unroll
    for (int o2 = 32; o2 > 0; o2 >>= 1) val += __shfl_down(val, o2, 64);
    if ((t & 63) == 0) {
        atomicAdd(&bkt[row & 255], val);
        atomicAdd(&hist[e], 1);
    }
}

// ---------- finalize loss + perplexity ----------
__global__ __launch_bounds__(256) void final_k(const float* __restrict__ bkt,
                                               const int* __restrict__ hist,
                                               float* __restrict__ out) {
    int t = threadIdx.x;
    double ls = (double)bkt[t];
    double ps = 0.0;
    for (int i = t; i < NUM_EMB; i += 256) {
        double p = (double)hist[i] / (double)N_ROWS;
        ps += p * log(p + 1e-10);
    }
    __shared__ double sdd[256], spp[256];
    sdd[t] = ls; spp[t] = ps;
    __syncthreads();
    for (int s = 128; s > 0; s >>= 1) {
        if (t < s) { sdd[t] += sdd[t + s]; spp[t] += spp[t + s]; }
        __syncthreads();
    }
    if (t == 0) {
        out[N_ELEM + 0] = (float)(1.25 * sdd[0] / (double)N_ELEM);
        out[N_ELEM + 1] = (float)exp(-spp[0]);
    }
}

extern "C" void kernel_launch(void* const* d_in, const int* in_sizes, int n_in,
                              void* d_out, int out_size, void* d_ws, size_t ws_size,
                              hipStream_t stream) {
    const float* x  = (const float*)d_in[0];
    const float* cb = (const float*)d_in[1];
    float* out = (float*)d_out;

    float* ws_f = (float*)d_ws;
    int*   ws_i = (int*)d_ws;
    int*   idx  = ws_i + IDX_OFF;
    float* xsq  = ws_f + XSQ_OFF;
    float* esq  = ws_f + ESQ_OFF;
    float* esqh = ws_f + ESQH_OFF;
    int*   hist = ws_i + HIST_OFF;
    float* bkt  = ws_f + BKT_OFF;
    int*   cnt  = ws_i + CNT_OFF;
    int*   flg  = ws_i + FLG_OFF;
    float* cbT  = ws_f + CBT_OFF;
    __half* cbTh = (__half*)(ws_f + CBTH_OFF);

    // x hi fp16 plane lives in d_out (overwritten by quant_k at the end)
    __half* xh = (__half*)d_out;

    hipMemsetAsync((char*)d_ws + (size_t)HIST_OFF * 4, 0,
                   (NUM_EMB + 256 + 1) * sizeof(float), stream);

    esq_k<<<NUM_EMB / 256, 256, 0, stream>>>(cb, esq, esqh);
    prep_cbt<<<128, 256, 0, stream>>>(cb, cbT, cbTh);
    prep_x<<<N_ROWS / 4, 256, 0, stream>>>(x, xh, xsq);
    argmin_mfma<<<N_ROWS / 64, 256, 0, stream>>>(xh, cbTh, esqh, idx, cnt, flg);
    fallback_k<<<512, 256, 0, stream>>>(x, cb, xsq, esq, cnt, flg, idx);
    quant_k<<<N_ROWS / 4, 256, 0, stream>>>(x, cbT, idx, out, bkt, hist);
    final_k<<<1, 256, 0, stream>>>(bkt, hist, out);
}

// Round 6
// 450.250 us; speedup vs baseline: 1.1499x; 1.1499x over previous
//
#include <hip/hip_runtime.h>
#include <hip/hip_fp16.h>
#include <math.h>

#define EMB_DIM 256
#define NUM_EMB 2048
#define N_ROWS  65536            // 64*32*32
#define N_ELEM  16777216         // N_ROWS * EMB_DIM
#define EPS_GAP 8e-3f            // ~10 sigma of 1-pass ordering error

// ---- workspace layout (in 4-byte elements) ----
#define IDX_OFF    0             // int[65536]
#define XSQ_OFF    65536         // float[65536]
#define ESQ_OFF    131072        // float[2048]  exact ||e||^2 (fallback)
#define ESQH_OFF   133120        // float[2048]  ||eh||^2 (fp16-rounded, main)
#define HIST_OFF   135168        // int[2048]
#define BKT_OFF    137216        // float[256]
#define CNT_OFF    137472        // int[1]
#define FLG_OFF    137473        // int[65536]
#define CBT_OFF    262144        // float[2048][256]  (transposed codebook)
#define CBTH_OFF   786432        // f16 [2048][256] hi plane (1 MB)

typedef __attribute__((ext_vector_type(8))) _Float16 half8;
typedef __attribute__((ext_vector_type(4))) float f32x4;
typedef unsigned int u32;

__device__ __forceinline__ void gl_lds16(const void* g, void* l) {
    __builtin_amdgcn_global_load_lds(
        (const __attribute__((address_space(1))) u32*)g,
        (__attribute__((address_space(3))) u32*)l, 16, 0, 0);
}

// ---------- prep: exact ||e||^2 (fallback) + ||eh||^2 (main, fp16-rounded) ----------
__global__ __launch_bounds__(256) void esq_k(const float* __restrict__ cb,
                                             float* __restrict__ esq,
                                             float* __restrict__ esqh) {
    int e = blockIdx.x * 256 + threadIdx.x;
    float s0 = 0.f, s1 = 0.f, s2 = 0.f, s3 = 0.f;
    float h0 = 0.f, h1 = 0.f, h2 = 0.f, h3 = 0.f;
    for (int d = 0; d < EMB_DIM; d += 4) {
        float c0 = cb[(d + 0) * NUM_EMB + e];
        float c1 = cb[(d + 1) * NUM_EMB + e];
        float c2 = cb[(d + 2) * NUM_EMB + e];
        float c3 = cb[(d + 3) * NUM_EMB + e];
        s0 = fmaf(c0, c0, s0); s1 = fmaf(c1, c1, s1);
        s2 = fmaf(c2, c2, s2); s3 = fmaf(c3, c3, s3);
        float q0 = __half2float(__float2half(c0));
        float q1 = __half2float(__float2half(c1));
        float q2 = __half2float(__float2half(c2));
        float q3 = __half2float(__float2half(c3));
        h0 = fmaf(q0, q0, h0); h1 = fmaf(q1, q1, h1);
        h2 = fmaf(q2, q2, h2); h3 = fmaf(q3, q3, h3);
    }
    esq[e]  = (s0 + s1) + (s2 + s3);
    esqh[e] = (h0 + h1) + (h2 + h3);
}

// ---------- prep: transpose codebook to [2048][256] fp32 + fp16 hi plane ----------
__global__ __launch_bounds__(256) void prep_cbt(const float* __restrict__ cb,
                                                float* __restrict__ cbT,
                                                __half* __restrict__ cbTh) {
    __shared__ float lt[64][65];
    int t = threadIdx.x;
    int et = (blockIdx.x & 31) * 64;   // e-tile base
    int dt = (blockIdx.x >> 5) * 64;   // d-tile base
    #pragma unroll
    for (int p = 0; p < 4; ++p) {
        int d  = p * 16 + (t >> 4);
        int e4 = (t & 15) * 4;
        const float4 v = *(const float4*)&cb[(dt + d) * NUM_EMB + et + e4];
        lt[d][e4] = v.x; lt[d][e4 + 1] = v.y; lt[d][e4 + 2] = v.z; lt[d][e4 + 3] = v.w;
    }
    __syncthreads();
    #pragma unroll
    for (int p = 0; p < 4; ++p) {
        int e  = p * 16 + (t >> 4);
        int d4 = (t & 15) * 4;
        float a[4] = {lt[d4][e], lt[d4 + 1][e], lt[d4 + 2][e], lt[d4 + 3][e]};
        *(float4*)&cbT[(et + e) * EMB_DIM + dt + d4] = make_float4(a[0], a[1], a[2], a[3]);
        unsigned short hb[4];
        #pragma unroll
        for (int i = 0; i < 4; ++i)
            hb[i] = __half_as_ushort(__float2half(a[i]));
        *(ushort4*)&cbTh[(et + e) * EMB_DIM + dt + d4] = make_ushort4(hb[0], hb[1], hb[2], hb[3]);
    }
}

// ---------- prep: x -> fp16 hi plane + ||x||^2 ----------
__global__ __launch_bounds__(256) void prep_x(const float* __restrict__ x,
                                              __half* __restrict__ xh,
                                              float* __restrict__ xsq) {
    int t = threadIdx.x;
    int row = blockIdx.x * 4 + (t >> 6);
    int c = (t & 63) * 4;
    const float4 v = *(const float4*)&x[row * EMB_DIM + c];
    float a[4] = {v.x, v.y, v.z, v.w};
    unsigned short hb[4];
    float s = 0.f;
    #pragma unroll
    for (int i = 0; i < 4; ++i) {
        hb[i] = __half_as_ushort(__float2half(a[i]));
        s = fmaf(a[i], a[i], s);
    }
    *(ushort4*)&xh[row * EMB_DIM + c] = make_ushort4(hb[0], hb[1], hb[2], hb[3]);
    #pragma unroll
    for (int o = 32; o > 0; o >>= 1) s += __shfl_down(s, o, 64);
    if ((t & 63) == 0) xsq[row] = s;
}

// ---------- main: 1-pass MFMA score + per-row argmin ----------
// Block = 64 rows, 4 waves; wave tile 64 rows x 64 cols (f=4,g=4); n-tile 256; 64 steps.
// Round-4-proven mod-3 counted-vmcnt pipeline: per step,
//   sched_barrier; vmcnt(5); s_barrier; sched_barrier; STAGE(step+2); ds_read; MFMA.
// STAGE = 5 loads/wave (1 A + 4 B); never drains to 0 in the main loop.
// acc[4][4]=64 regs (f=4,g=8 spilled at 128 — round-5 lesson, WRITE_SIZE 174 MB).
// score v = ||eh||^2 - 2*(xh . eh); ordering error ~8e-4 pairwise, EPS_GAP = 8e-3.
#define BUFH 10240   // halfs per LDS buffer: A 2048 + B 8192  (20 KB)
__global__ __launch_bounds__(256, 2) void argmin_mfma(
    const __half* __restrict__ xh_, const __half* __restrict__ cbh_,
    const float* __restrict__ esqh,
    int* __restrict__ idx_out, int* __restrict__ cnt, int* __restrict__ flg) {

    __shared__ _Float16 ldsbuf[3 * BUFH];          // 60 KB -> 2 blocks/CU
    _Float16* lds = ldsbuf;

    const _Float16* xh  = (const _Float16*)xh_;
    const _Float16* cbh = (const _Float16*)cbh_;

    const int t = threadIdx.x;
    const int w = t >> 6, L = t & 63;
    const int wn = w * 64;                         // wave's column base within n-tile
    const int lm = L & 15, lq = L >> 4;
    const int ph = (lm >> 1) & 3;                  // frag-read XOR swizzle phase
    const int rowbase = blockIdx.x * 64;

    // staging geometry: each gl_lds16 stages 16 rows (64 lanes x 8 halfs, lane-linear dest)
    const int srow = L >> 2;                       // row within 16-row group
    const int sq   = (L & 3) ^ ((L >> 3) & 3);     // swizzled source chunk (x8 f16)

    const _Float16* pa  = xh + (size_t)(rowbase + w * 16 + srow) * EMB_DIM + sq * 8;
    const _Float16* pb0 = cbh + (size_t)(w * 16 + srow) * EMB_DIM + sq * 8;
    const int oA = (w * 16) * 32;                  // A region [64][32] at +0
    const int oB = 2048 + (w * 16) * 32;           // B region [256][32] at +2048

    float best[16], b2[16];
    int   bi[16];
    #pragma unroll
    for (int s = 0; s < 16; ++s) { best[s] = 3.4e38f; b2[s] = 3.4e38f; bi[s] = 0; }

    // stage group gs (step = nt*8+kt) into buffer bb: 1 A line + 4 B lines = 5 loads
    #define STAGE(gs, bb) do {                                                   \
        const int nnt_ = (gs) >> 3, nkt_ = (gs) & 7;                             \
        const int ko_  = nkt_ * 32;                                              \
        const _Float16* pb_ = pb0 + ((size_t)nnt_ * 256) * EMB_DIM + ko_;        \
        gl_lds16(pa + ko_, (bb) + oA);                                           \
        gl_lds16(pb_ +   0 * EMB_DIM, (bb) + oB +    0);                         \
        gl_lds16(pb_ +  64 * EMB_DIM, (bb) + oB + 2048);                         \
        gl_lds16(pb_ + 128 * EMB_DIM, (bb) + oB + 4096);                         \
        gl_lds16(pb_ + 192 * EMB_DIM, (bb) + oB + 6144);                         \
    } while (0)

    // prologue: stage groups 0 and 1 into buffers 0 and 1
    STAGE(0, lds);
    STAGE(1, lds + BUFH);

    for (int nt = 0; nt < 8; ++nt) {
        // per-nt esqh preload (4 VMEM loads; vmcnt(5) stays safe: >=5 newer loads in flight)
        float eq[4];
        #pragma unroll
        for (int g = 0; g < 4; ++g)
            eq[g] = esqh[nt * 256 + wn + g * 16 + lm];

        f32x4 acc[4][4];
        #pragma unroll
        for (int f = 0; f < 4; ++f)
            #pragma unroll
            for (int g = 0; g < 4; ++g)
                acc[f][g] = (f32x4){0.f, 0.f, 0.f, 0.f};

        for (int kt = 0; kt < 8; ++kt) {
            const int step = nt * 8 + kt;

            // pin prior step's ds_reads/MFMAs above the sync point
            __builtin_amdgcn_sched_barrier(0);
            if (step < 63) {
                asm volatile("s_waitcnt vmcnt(5)" ::: "memory");   // group-step retired; newer in flight
            } else {
                asm volatile("s_waitcnt vmcnt(0)" ::: "memory");   // final step: drain
            }
            __builtin_amdgcn_s_barrier();          // group-step writes visible to all waves
            __builtin_amdgcn_sched_barrier(0);

            // issue group step+2 into buf[(step+2)%3]
            if (step < 62)
                STAGE(step + 2, lds + ((step + 2) % 3) * BUFH);

            // compute current step from buf[step%3]
            const _Float16* sa = lds + (step % 3) * BUFH;
            const _Float16* sb = sa + 2048;

            half8 ah[4], bh[4];
            #pragma unroll
            for (int f = 0; f < 4; ++f)
                ah[f] = *(const half8*)&sa[(f * 16 + lm) * 32 + ((lq ^ ph) * 8)];
            #pragma unroll
            for (int g = 0; g < 4; ++g)
                bh[g] = *(const half8*)&sb[(wn + g * 16 + lm) * 32 + ((lq ^ ph) * 8)];

            __builtin_amdgcn_s_setprio(1);
            #pragma unroll
            for (int f = 0; f < 4; ++f)
                #pragma unroll
                for (int g = 0; g < 4; ++g)
                    acc[f][g] = __builtin_amdgcn_mfma_f32_16x16x32_f16(ah[f], bh[g], acc[f][g], 0, 0, 0);
            __builtin_amdgcn_s_setprio(0);
        }

        // epilogue: v = esqh - 2*sim; running (best, second, index); cols ascend -> strict <
        #pragma unroll
        for (int g = 0; g < 4; ++g) {
            int col = nt * 256 + wn + g * 16 + lm;
            #pragma unroll
            for (int f = 0; f < 4; ++f)
                #pragma unroll
                for (int r = 0; r < 4; ++r) {
                    int s = f * 4 + r;
                    float v = fmaf(-2.0f, acc[f][g][r], eq[g]);
                    float bo = best[s];
                    b2[s]   = fminf(b2[s], fmaxf(bo, v));
                    best[s] = fminf(bo, v);
                    bi[s]   = (v < bo) ? col : bi[s];
                }
        }
    }
    #undef STAGE

    // block-level reduce: 64 candidates per row; pitch 65 -> conflict-free column scan
    __syncthreads();
    float* smemf = (float*)ldsbuf;
    float* rd = smemf;                  // [64][65]
    int*   ri = (int*)(smemf + 4160);
    float* r2 = smemf + 8320;           // 12480 floats = 49.9 KB <= 60 KB
    #pragma unroll
    for (int f = 0; f < 4; ++f)
        #pragma unroll
        for (int r = 0; r < 4; ++r) {
            int row = f * 16 + lq * 4 + r;
            int c = w * 16 + lm;
            rd[row * 65 + c] = best[f * 4 + r];
            ri[row * 65 + c] = bi[f * 4 + r];
            r2[row * 65 + c] = b2[f * 4 + r];
        }
    __syncthreads();
    if (t < 64) {
        int row = t;
        float g1 = rd[row * 65]; int gi = ri[row * 65]; float g2 = r2[row * 65];
        for (int c = 1; c < 64; ++c) {
            float d = rd[row * 65 + c]; int ic = ri[row * 65 + c]; float d2 = r2[row * 65 + c];
            if (d < g1 || (d == g1 && ic < gi)) { g2 = fminf(g1, d2); g1 = d; gi = ic; }
            else g2 = fminf(g2, d);
        }
        idx_out[rowbase + row] = gi;
        if (g2 - g1 < EPS_GAP) {       // near-tie: route to exact fp32 fallback
            int p = atomicAdd(cnt, 1);
            flg[p] = rowbase + row;
        }
    }
}

// ---------- exact fp32 re-check for flagged (near-tie) rows ----------
// Coalesced + 4-row batched: cb original [256][2048] layout, lane t owns codes
// {t, 256+t, ...}; per-thread accumulation replicates the reference-matching
// 4-partial-sum structure -> bitwise-identical candidates.
__global__ __launch_bounds__(256) void fallback_k(const float* __restrict__ x,
                                                  const float* __restrict__ cb,
                                                  const float* __restrict__ xsq,
                                                  const float* __restrict__ esq,
                                                  const int* __restrict__ cnt,
                                                  const int* __restrict__ rows,
                                                  int* __restrict__ idx) {
    __shared__ float xr[4][256];
    __shared__ float sd[4][256];
    __shared__ int   si[4][256];
    int t = threadIdx.x;
    int n = *cnt;
    for (int base = blockIdx.x * 4; base < n; base += gridDim.x * 4) {
        int rws[4];
        #pragma unroll
        for (int r = 0; r < 4; ++r) {
            int fi = base + r;
            rws[r] = rows[(fi < n) ? fi : (n - 1)];   // pad by repeating last (benign)
        }
        __syncthreads();   // WAR vs previous group's reduce
        #pragma unroll
        for (int r = 0; r < 4; ++r) xr[r][t] = x[(size_t)rws[r] * EMB_DIM + t];
        __syncthreads();

        float bd[4]; int bidx[4];
        #pragma unroll
        for (int r = 0; r < 4; ++r) { bd[r] = 3.4e38f; bidx[r] = 0x7fffffff; }

        for (int j = 0; j < 8; ++j) {
            int e = j * 256 + t;
            float s0[4], s1[4], s2[4], s3[4];
            #pragma unroll
            for (int r = 0; r < 4; ++r) { s0[r] = 0.f; s1[r] = 0.f; s2[r] = 0.f; s3[r] = 0.f; }
            for (int d = 0; d < EMB_DIM; d += 4) {
                float c0 = cb[(size_t)(d + 0) * NUM_EMB + e];
                float c1 = cb[(size_t)(d + 1) * NUM_EMB + e];
                float c2 = cb[(size_t)(d + 2) * NUM_EMB + e];
                float c3 = cb[(size_t)(d + 3) * NUM_EMB + e];
                #pragma unroll
                for (int r = 0; r < 4; ++r) {
                    const float4 xv = *(const float4*)&xr[r][d];
                    s0[r] = fmaf(xv.x, c0, s0[r]);
                    s1[r] = fmaf(xv.y, c1, s1[r]);
                    s2[r] = fmaf(xv.z, c2, s2[r]);
                    s3[r] = fmaf(xv.w, c3, s3[r]);
                }
            }
            float eqv = esq[e];
            #pragma unroll
            for (int r = 0; r < 4; ++r) {
                float sim = (s0[r] + s1[r]) + (s2[r] + s3[r]);
                float dd = (xsq[rws[r]] + eqv) - 2.0f * sim;
                if (dd < bd[r]) { bd[r] = dd; bidx[r] = e; }   // e ascends per thread
            }
        }
        #pragma unroll
        for (int r = 0; r < 4; ++r) { sd[r][t] = bd[r]; si[r][t] = bidx[r]; }
        __syncthreads();
        for (int r = 0; r < 4; ++r) {
            for (int stp = 128; stp > 0; stp >>= 1) {
                if (t < stp) {
                    if (sd[r][t + stp] < sd[r][t] ||
                        (sd[r][t + stp] == sd[r][t] && si[r][t + stp] < si[r][t])) {
                        sd[r][t] = sd[r][t + stp]; si[r][t] = si[r][t + stp];
                    }
                }
                __syncthreads();
            }
        }
        if (t == 0) {
            #pragma unroll
            for (int r = 0; r < 4; ++r) idx[rws[r]] = si[r][0];
        }
    }
}

// ---------- quantize + straight-through + loss partials + histogram ----------
__global__ __launch_bounds__(256) void quant_k(const float* __restrict__ x,
                                               const float* __restrict__ cbT,
                                               const int* __restrict__ idx,
                                               float* __restrict__ out,
                                               float* __restrict__ bkt,
                                               int* __restrict__ hist) {
    int t = threadIdx.x;
    int row = blockIdx.x * 4 + (t >> 6);
    int c = (t & 63) * 4;
    int e = idx[row];
    const float4 q  = *(const float4*)&cbT[(size_t)e * EMB_DIM + c];
    const float4 xv = *(const float4*)&x[(size_t)row * EMB_DIM + c];
    float4 o;
    o.x = xv.x + (q.x - xv.x); o.y = xv.y + (q.y - xv.y);
    o.z = xv.z + (q.z - xv.z); o.w = xv.w + (q.w - xv.w);
    *(float4*)&out[(size_t)row * EMB_DIM + c] = o;
    float dx = xv.x - q.x, dy = xv.y - q.y, dz = xv.z - q.z, dw = xv.w - q.w;
    float val = fmaf(dx, dx, 0.f);
    val = fmaf(dy, dy, val);
    val = fmaf(dz, dz, val);
    val = fmaf(dw, dw, val);
    #pragma unroll
    for (int o2 = 32; o2 > 0; o2 >>= 1) val += __shfl_down(val, o2, 64);
    if ((t & 63) == 0) {
        atomicAdd(&bkt[row & 255], val);
        atomicAdd(&hist[e], 1);
    }
}

// ---------- finalize loss + perplexity ----------
__global__ __launch_bounds__(256) void final_k(const float* __restrict__ bkt,
                                               const int* __restrict__ hist,
                                               float* __restrict__ out) {
    int t = threadIdx.x;
    double ls = (double)bkt[t];
    double ps = 0.0;
    for (int i = t; i < NUM_EMB; i += 256) {
        double p = (double)hist[i] / (double)N_ROWS;
        ps += p * log(p + 1e-10);
    }
    __shared__ double sdd[256], spp[256];
    sdd[t] = ls; spp[t] = ps;
    __syncthreads();
    for (int s = 128; s > 0; s >>= 1) {
        if (t < s) { sdd[t] += sdd[t + s]; spp[t] += spp[t + s]; }
        __syncthreads();
    }
    if (t == 0) {
        out[N_ELEM + 0] = (float)(1.25 * sdd[0] / (double)N_ELEM);
        out[N_ELEM + 1] = (float)exp(-spp[0]);
    }
}

extern "C" void kernel_launch(void* const* d_in, const int* in_sizes, int n_in,
                              void* d_out, int out_size, void* d_ws, size_t ws_size,
                              hipStream_t stream) {
    const float* x  = (const float*)d_in[0];
    const float* cb = (const float*)d_in[1];
    float* out = (float*)d_out;

    float* ws_f = (float*)d_ws;
    int*   ws_i = (int*)d_ws;
    int*   idx  = ws_i + IDX_OFF;
    float* xsq  = ws_f + XSQ_OFF;
    float* esq  = ws_f + ESQ_OFF;
    float* esqh = ws_f + ESQH_OFF;
    int*   hist = ws_i + HIST_OFF;
    float* bkt  = ws_f + BKT_OFF;
    int*   cnt  = ws_i + CNT_OFF;
    int*   flg  = ws_i + FLG_OFF;
    float* cbT  = ws_f + CBT_OFF;
    __half* cbTh = (__half*)(ws_f + CBTH_OFF);

    // x hi fp16 plane lives in d_out (overwritten by quant_k at the end)
    __half* xh = (__half*)d_out;

    hipMemsetAsync((char*)d_ws + (size_t)HIST_OFF * 4, 0,
                   (NUM_EMB + 256 + 1) * sizeof(float), stream);

    esq_k<<<NUM_EMB / 256, 256, 0, stream>>>(cb, esq, esqh);
    prep_cbt<<<128, 256, 0, stream>>>(cb, cbT, cbTh);
    prep_x<<<N_ROWS / 4, 256, 0, stream>>>(x, xh, xsq);
    argmin_mfma<<<N_ROWS / 64, 256, 0, stream>>>(xh, cbTh, esqh, idx, cnt, flg);
    fallback_k<<<512, 256, 0, stream>>>(x, cb, xsq, esq, cnt, flg, idx);
    quant_k<<<N_ROWS / 4, 256, 0, stream>>>(x, cbT, idx, out, bkt, hist);
    final_k<<<1, 256, 0, stream>>>(bkt, hist, out);
}

// Round 7
// 431.614 us; speedup vs baseline: 1.1996x; 1.0432x over previous
//
#include <hip/hip_runtime.h>
#include <hip/hip_fp16.h>
#include <math.h>

#define EMB_DIM 256
#define NUM_EMB 2048
#define N_ROWS  65536            // 64*32*32
#define N_ELEM  16777216         // N_ROWS * EMB_DIM
#define EPS_GAP 8e-3f            // ~10 sigma of 1-pass ordering error

// ---- workspace layout (in 4-byte elements) ----
#define IDX_OFF    0             // int[65536]
#define XSQ_OFF    65536         // float[65536]
#define ESQ_OFF    131072        // float[2048]  exact ||e||^2 (fallback)
#define ESQH_OFF   133120        // float[2048]  ||eh||^2 (fp16-rounded, main)
#define HIST_OFF   135168        // int[2048]
#define BKT_OFF    137216        // float[256]
#define CNT_OFF    137472        // int[1]
#define FLG_OFF    137473        // int[65536]
#define CBT_OFF    262144        // float[2048][256]  (transposed codebook)
#define CBTH_OFF   786432        // f16 [2048][256] hi plane (1 MB)

typedef __attribute__((ext_vector_type(8))) _Float16 half8;
typedef __attribute__((ext_vector_type(4))) float f32x4;
typedef unsigned int u32;

__device__ __forceinline__ void gl_lds16(const void* g, void* l) {
    __builtin_amdgcn_global_load_lds(
        (const __attribute__((address_space(1))) u32*)g,
        (__attribute__((address_space(3))) u32*)l, 16, 0, 0);
}

// ---------- fused prep: esq (blocks 0-7) + cbt transpose (8-135) + x fp16 (136+) ----------
// Bodies verbatim from the verified standalone kernels -> bit-identical outputs.
// Small sections run concurrently with (and hide under) the 16384 prep_x blocks.
__global__ __launch_bounds__(256) void prep_all(
    const float* __restrict__ x, const float* __restrict__ cb,
    float* __restrict__ esq, float* __restrict__ esqh,
    float* __restrict__ cbT, __half* __restrict__ cbTh,
    __half* __restrict__ xh, float* __restrict__ xsq) {
    __shared__ float lt[64][65];
    const int bid = blockIdx.x;
    const int t = threadIdx.x;
    if (bid < 8) {
        // ---- esq section: exact ||e||^2 + ||eh||^2 ----
        int e = bid * 256 + t;
        float s0 = 0.f, s1 = 0.f, s2 = 0.f, s3 = 0.f;
        float h0 = 0.f, h1 = 0.f, h2 = 0.f, h3 = 0.f;
        for (int d = 0; d < EMB_DIM; d += 4) {
            float c0 = cb[(d + 0) * NUM_EMB + e];
            float c1 = cb[(d + 1) * NUM_EMB + e];
            float c2 = cb[(d + 2) * NUM_EMB + e];
            float c3 = cb[(d + 3) * NUM_EMB + e];
            s0 = fmaf(c0, c0, s0); s1 = fmaf(c1, c1, s1);
            s2 = fmaf(c2, c2, s2); s3 = fmaf(c3, c3, s3);
            float q0 = __half2float(__float2half(c0));
            float q1 = __half2float(__float2half(c1));
            float q2 = __half2float(__float2half(c2));
            float q3 = __half2float(__float2half(c3));
            h0 = fmaf(q0, q0, h0); h1 = fmaf(q1, q1, h1);
            h2 = fmaf(q2, q2, h2); h3 = fmaf(q3, q3, h3);
        }
        esq[e]  = (s0 + s1) + (s2 + s3);
        esqh[e] = (h0 + h1) + (h2 + h3);
    } else if (bid < 136) {
        // ---- codebook transpose section ----
        int b = bid - 8;
        int et = (b & 31) * 64;   // e-tile base
        int dt = (b >> 5) * 64;   // d-tile base
        #pragma unroll
        for (int p = 0; p < 4; ++p) {
            int d  = p * 16 + (t >> 4);
            int e4 = (t & 15) * 4;
            const float4 v = *(const float4*)&cb[(dt + d) * NUM_EMB + et + e4];
            lt[d][e4] = v.x; lt[d][e4 + 1] = v.y; lt[d][e4 + 2] = v.z; lt[d][e4 + 3] = v.w;
        }
        __syncthreads();
        #pragma unroll
        for (int p = 0; p < 4; ++p) {
            int e  = p * 16 + (t >> 4);
            int d4 = (t & 15) * 4;
            float a[4] = {lt[d4][e], lt[d4 + 1][e], lt[d4 + 2][e], lt[d4 + 3][e]};
            *(float4*)&cbT[(et + e) * EMB_DIM + dt + d4] = make_float4(a[0], a[1], a[2], a[3]);
            unsigned short hb[4];
            #pragma unroll
            for (int i = 0; i < 4; ++i)
                hb[i] = __half_as_ushort(__float2half(a[i]));
            *(ushort4*)&cbTh[(et + e) * EMB_DIM + dt + d4] = make_ushort4(hb[0], hb[1], hb[2], hb[3]);
        }
    } else {
        // ---- x -> fp16 hi plane + ||x||^2 section ----
        int b = bid - 136;
        int row = b * 4 + (t >> 6);
        int c = (t & 63) * 4;
        const float4 v = *(const float4*)&x[row * EMB_DIM + c];
        float a[4] = {v.x, v.y, v.z, v.w};
        unsigned short hb[4];
        float s = 0.f;
        #pragma unroll
        for (int i = 0; i < 4; ++i) {
            hb[i] = __half_as_ushort(__float2half(a[i]));
            s = fmaf(a[i], a[i], s);
        }
        *(ushort4*)&xh[row * EMB_DIM + c] = make_ushort4(hb[0], hb[1], hb[2], hb[3]);
        #pragma unroll
        for (int o = 32; o > 0; o >>= 1) s += __shfl_down(s, o, 64);
        if ((t & 63) == 0) xsq[row] = s;
    }
}

// ---------- main: 1-pass MFMA score + per-row argmin ----------
// Block = 64 rows, 4 waves; wave tile 64x64 (f=4,g=4); n-tile 256.
// MACRO-STEP = K=64 (two verified BK-32 sub-tiles, layouts concatenated, addressing
// verbatim per sub-tile). 32 macro-steps; double-buffered 2x40 KB; depth-1 pipeline:
//   vmcnt(0)[group S ~800cyc old]; barrier; STAGE(S+1); 16 ds_read; lgkmcnt; barrier(WAR);
//   32 MFMA (setprio).
// Per-acc K order = ascending (h=0 then h=1) -> bitwise-identical scores to round 6.
// Registers: 64 frag VGPR + 48 state + ~30 addr + 64 acc AGPR ~ 210 < 256 (no spill).
#define BUFH 20480   // halfs per buffer: A0 2048 + A1 2048 + B0 8192 + B1 8192 (40 KB)
__global__ __launch_bounds__(256, 2) void argmin_mfma(
    const __half* __restrict__ xh_, const __half* __restrict__ cbh_,
    const float* __restrict__ esqh,
    int* __restrict__ idx_out, int* __restrict__ cnt, int* __restrict__ flg) {

    __shared__ _Float16 ldsbuf[2 * BUFH];          // 80 KB -> 2 blocks/CU
    _Float16* lds = ldsbuf;

    const _Float16* xh  = (const _Float16*)xh_;
    const _Float16* cbh = (const _Float16*)cbh_;

    const int t = threadIdx.x;
    const int w = t >> 6, L = t & 63;
    const int wn = w * 64;                         // wave's column base within n-tile
    const int lm = L & 15, lq = L >> 4;
    const int ph = (lm >> 1) & 3;                  // frag-read XOR swizzle phase
    const int rowbase = blockIdx.x * 64;

    // staging geometry: each gl_lds16 stages 16 rows (64 lanes x 8 halfs, lane-linear dest)
    const int srow = L >> 2;                       // row within 16-row group
    const int sq   = (L & 3) ^ ((L >> 3) & 3);     // swizzled source chunk (x8 f16)

    const _Float16* pa  = xh + (size_t)(rowbase + w * 16 + srow) * EMB_DIM + sq * 8;
    const _Float16* pb0 = cbh + (size_t)(w * 16 + srow) * EMB_DIM + sq * 8;
    const int oA = (w * 16) * 32;                  // wave's A row-group offset (per sub-tile)
    const int oB = (w * 16) * 32;                  // wave's B row-group offset (per sub-tile)

    float best[16], b2[16];
    int   bi[16];
    #pragma unroll
    for (int s = 0; s < 16; ++s) { best[s] = 3.4e38f; b2[s] = 3.4e38f; bi[s] = 0; }

    // stage macro-group S (nt = S>>2, K-base = (S&3)*64) into buffer bb: 2 A + 8 B lines
    #define STAGE(S_, bb) do {                                                   \
        const int nnt_ = (S_) >> 2;                                              \
        const int km_  = ((S_) & 3) * 64;                                        \
        const _Float16* pb_ = pb0 + (size_t)nnt_ * 256 * EMB_DIM + km_;          \
        gl_lds16(pa + km_,                 (bb) + oA);                           \
        gl_lds16(pa + km_ + 32,            (bb) + 2048 + oA);                    \
        gl_lds16(pb_ +   0 * EMB_DIM,      (bb) + 4096 + oB);                    \
        gl_lds16(pb_ +  64 * EMB_DIM,      (bb) + 4096 + oB + 2048);             \
        gl_lds16(pb_ + 128 * EMB_DIM,      (bb) + 4096 + oB + 4096);             \
        gl_lds16(pb_ + 192 * EMB_DIM,      (bb) + 4096 + oB + 6144);             \
        gl_lds16(pb_ +   0 * EMB_DIM + 32, (bb) + 12288 + oB);                   \
        gl_lds16(pb_ +  64 * EMB_DIM + 32, (bb) + 12288 + oB + 2048);            \
        gl_lds16(pb_ + 128 * EMB_DIM + 32, (bb) + 12288 + oB + 4096);            \
        gl_lds16(pb_ + 192 * EMB_DIM + 32, (bb) + 12288 + oB + 6144);            \
    } while (0)

    // prologue: stage macro-group 0 into buffer 0
    STAGE(0, lds);

    for (int nt = 0; nt < 8; ++nt) {
        // per-nt esqh preload (drained by the next macro-step's vmcnt(0))
        float eq[4];
        #pragma unroll
        for (int g = 0; g < 4; ++g)
            eq[g] = esqh[nt * 256 + wn + g * 16 + lm];

        f32x4 acc[4][4];
        #pragma unroll
        for (int f = 0; f < 4; ++f)
            #pragma unroll
            for (int g = 0; g < 4; ++g)
                acc[f][g] = (f32x4){0.f, 0.f, 0.f, 0.f};

        for (int mt = 0; mt < 4; ++mt) {
            const int S = nt * 4 + mt;

            // group S was issued one full macro-step (~800+ cyc) ago; wait is cheap
            __builtin_amdgcn_sched_barrier(0);
            asm volatile("s_waitcnt vmcnt(0)" ::: "memory");
            __builtin_amdgcn_s_barrier();          // publish: group S visible to all waves
            __builtin_amdgcn_sched_barrier(0);

            // issue next macro-group into the other buffer (WAR held by prev step's barrier B)
            if (S < 31)
                STAGE(S + 1, lds + ((S + 1) & 1) * BUFH);

            const _Float16* bb = lds + (S & 1) * BUFH;

            half8 ah[2][4], bh[2][4];
            #pragma unroll
            for (int h = 0; h < 2; ++h)
                #pragma unroll
                for (int f = 0; f < 4; ++f)
                    ah[h][f] = *(const half8*)&bb[h * 2048 + (f * 16 + lm) * 32 + ((lq ^ ph) * 8)];
            #pragma unroll
            for (int h = 0; h < 2; ++h)
                #pragma unroll
                for (int g = 0; g < 4; ++g)
                    bh[h][g] = *(const half8*)&bb[4096 + h * 8192 + (wn + g * 16 + lm) * 32 + ((lq ^ ph) * 8)];

            asm volatile("s_waitcnt lgkmcnt(0)" ::: "memory");   // frag reads retired
            __builtin_amdgcn_sched_barrier(0);
            __builtin_amdgcn_s_barrier();          // WAR: buf[S&1] free for staging S+2
            __builtin_amdgcn_sched_barrier(0);

            __builtin_amdgcn_s_setprio(1);
            #pragma unroll
            for (int h = 0; h < 2; ++h)            // K ascending per acc -> bit-identical
                #pragma unroll
                for (int f = 0; f < 4; ++f)
                    #pragma unroll
                    for (int g = 0; g < 4; ++g)
                        acc[f][g] = __builtin_amdgcn_mfma_f32_16x16x32_f16(ah[h][f], bh[h][g], acc[f][g], 0, 0, 0);
            __builtin_amdgcn_s_setprio(0);
        }

        // epilogue: v = esqh - 2*sim; running (best, second, index); cols ascend -> strict <
        #pragma unroll
        for (int g = 0; g < 4; ++g) {
            int col = nt * 256 + wn + g * 16 + lm;
            #pragma unroll
            for (int f = 0; f < 4; ++f)
                #pragma unroll
                for (int r = 0; r < 4; ++r) {
                    int s = f * 4 + r;
                    float v = fmaf(-2.0f, acc[f][g][r], eq[g]);
                    float bo = best[s];
                    b2[s]   = fminf(b2[s], fmaxf(bo, v));
                    best[s] = fminf(bo, v);
                    bi[s]   = (v < bo) ? col : bi[s];
                }
        }
    }
    #undef STAGE

    // block-level reduce: 64 candidates per row; pitch 65 -> conflict-free column scan
    __syncthreads();
    float* smemf = (float*)ldsbuf;
    float* rd = smemf;                  // [64][65]
    int*   ri = (int*)(smemf + 4160);
    float* r2 = smemf + 8320;           // 12480 floats = 49.9 KB <= 80 KB
    #pragma unroll
    for (int f = 0; f < 4; ++f)
        #pragma unroll
        for (int r = 0; r < 4; ++r) {
            int row = f * 16 + lq * 4 + r;
            int c = w * 16 + lm;
            rd[row * 65 + c] = best[f * 4 + r];
            ri[row * 65 + c] = bi[f * 4 + r];
            r2[row * 65 + c] = b2[f * 4 + r];
        }
    __syncthreads();
    if (t < 64) {
        int row = t;
        float g1 = rd[row * 65]; int gi = ri[row * 65]; float g2 = r2[row * 65];
        for (int c = 1; c < 64; ++c) {
            float d = rd[row * 65 + c]; int ic = ri[row * 65 + c]; float d2 = r2[row * 65 + c];
            if (d < g1 || (d == g1 && ic < gi)) { g2 = fminf(g1, d2); g1 = d; gi = ic; }
            else g2 = fminf(g2, d);
        }
        idx_out[rowbase + row] = gi;
        if (g2 - g1 < EPS_GAP) {       // near-tie: route to exact fp32 fallback
            int p = atomicAdd(cnt, 1);
            flg[p] = rowbase + row;
        }
    }
}

// ---------- exact fp32 re-check for flagged (near-tie) rows ----------
// Coalesced + 4-row batched: cb original [256][2048] layout, lane t owns codes
// {t, 256+t, ...}; per-thread accumulation replicates the reference-matching
// 4-partial-sum structure -> bitwise-identical candidates.
__global__ __launch_bounds__(256) void fallback_k(const float* __restrict__ x,
                                                  const float* __restrict__ cb,
                                                  const float* __restrict__ xsq,
                                                  const float* __restrict__ esq,
                                                  const int* __restrict__ cnt,
                                                  const int* __restrict__ rows,
                                                  int* __restrict__ idx) {
    __shared__ float xr[4][256];
    __shared__ float sd[4][256];
    __shared__ int   si[4][256];
    int t = threadIdx.x;
    int n = *cnt;
    for (int base = blockIdx.x * 4; base < n; base += gridDim.x * 4) {
        int rws[4];
        #pragma unroll
        for (int r = 0; r < 4; ++r) {
            int fi = base + r;
            rws[r] = rows[(fi < n) ? fi : (n - 1)];   // pad by repeating last (benign)
        }
        __syncthreads();   // WAR vs previous group's reduce
        #pragma unroll
        for (int r = 0; r < 4; ++r) xr[r][t] = x[(size_t)rws[r] * EMB_DIM + t];
        __syncthreads();

        float bd[4]; int bidx[4];
        #pragma unroll
        for (int r = 0; r < 4; ++r) { bd[r] = 3.4e38f; bidx[r] = 0x7fffffff; }

        for (int j = 0; j < 8; ++j) {
            int e = j * 256 + t;
            float s0[4], s1[4], s2[4], s3[4];
            #pragma unroll
            for (int r = 0; r < 4; ++r) { s0[r] = 0.f; s1[r] = 0.f; s2[r] = 0.f; s3[r] = 0.f; }
            for (int d = 0; d < EMB_DIM; d += 4) {
                float c0 = cb[(size_t)(d + 0) * NUM_EMB + e];
                float c1 = cb[(size_t)(d + 1) * NUM_EMB + e];
                float c2 = cb[(size_t)(d + 2) * NUM_EMB + e];
                float c3 = cb[(size_t)(d + 3) * NUM_EMB + e];
                #pragma unroll
                for (int r = 0; r < 4; ++r) {
                    const float4 xv = *(const float4*)&xr[r][d];
                    s0[r] = fmaf(xv.x, c0, s0[r]);
                    s1[r] = fmaf(xv.y, c1, s1[r]);
                    s2[r] = fmaf(xv.z, c2, s2[r]);
                    s3[r] = fmaf(xv.w, c3, s3[r]);
                }
            }
            float eqv = esq[e];
            #pragma unroll
            for (int r = 0; r < 4; ++r) {
                float sim = (s0[r] + s1[r]) + (s2[r] + s3[r]);
                float dd = (xsq[rws[r]] + eqv) - 2.0f * sim;
                if (dd < bd[r]) { bd[r] = dd; bidx[r] = e; }   // e ascends per thread
            }
        }
        #pragma unroll
        for (int r = 0; r < 4; ++r) { sd[r][t] = bd[r]; si[r][t] = bidx[r]; }
        __syncthreads();
        for (int r = 0; r < 4; ++r) {
            for (int stp = 128; stp > 0; stp >>= 1) {
                if (t < stp) {
                    if (sd[r][t + stp] < sd[r][t] ||
                        (sd[r][t + stp] == sd[r][t] && si[r][t + stp] < si[r][t])) {
                        sd[r][t] = sd[r][t + stp]; si[r][t] = si[r][t + stp];
                    }
                }
                __syncthreads();
            }
        }
        if (t == 0) {
            #pragma unroll
            for (int r = 0; r < 4; ++r) idx[rws[r]] = si[r][0];
        }
    }
}

// ---------- quantize + straight-through + loss partials + histogram ----------
__global__ __launch_bounds__(256) void quant_k(const float* __restrict__ x,
                                               const float* __restrict__ cbT,
                                               const int* __restrict__ idx,
                                               float* __restrict__ out,
                                               float* __restrict__ bkt,
                                               int* __restrict__ hist) {
    int t = threadIdx.x;
    int row = blockIdx.x * 4 + (t >> 6);
    int c = (t & 63) * 4;
    int e = idx[row];
    const float4 q  = *(const float4*)&cbT[(size_t)e * EMB_DIM + c];
    const float4 xv = *(const float4*)&x[(size_t)row * EMB_DIM + c];
    float4 o;
    o.x = xv.x + (q.x - xv.x); o.y = xv.y + (q.y - xv.y);
    o.z = xv.z + (q.z - xv.z); o.w = xv.w + (q.w - xv.w);
    *(float4*)&out[(size_t)row * EMB_DIM + c] = o;
    float dx = xv.x - q.x, dy = xv.y - q.y, dz = xv.z - q.z, dw = xv.w - q.w;
    float val = fmaf(dx, dx, 0.f);
    val = fmaf(dy, dy, val);
    val = fmaf(dz, dz, val);
    val = fmaf(dw, dw, val);
    #pragma unroll
    for (int o2 = 32; o2 > 0; o2 >>= 1) val += __shfl_down(val, o2, 64);
    if ((t & 63) == 0) {
        atomicAdd(&bkt[row & 255], val);
        atomicAdd(&hist[e], 1);
    }
}

// ---------- finalize loss + perplexity ----------
__global__ __launch_bounds__(256) void final_k(const float* __restrict__ bkt,
                                               const int* __restrict__ hist,
                                               float* __restrict__ out) {
    int t = threadIdx.x;
    double ls = (double)bkt[t];
    double ps = 0.0;
    for (int i = t; i < NUM_EMB; i += 256) {
        double p = (double)hist[i] / (double)N_ROWS;
        ps += p * log(p + 1e-10);
    }
    __shared__ double sdd[256], spp[256];
    sdd[t] = ls; spp[t] = ps;
    __syncthreads();
    for (int s = 128; s > 0; s >>= 1) {
        if (t < s) { sdd[t] += sdd[t + s]; spp[t] += spp[t + s]; }
        __syncthreads();
    }
    if (t == 0) {
        out[N_ELEM + 0] = (float)(1.25 * sdd[0] / (double)N_ELEM);
        out[N_ELEM + 1] = (float)exp(-spp[0]);
    }
}

extern "C" void kernel_launch(void* const* d_in, const int* in_sizes, int n_in,
                              void* d_out, int out_size, void* d_ws, size_t ws_size,
                              hipStream_t stream) {
    const float* x  = (const float*)d_in[0];
    const float* cb = (const float*)d_in[1];
    float* out = (float*)d_out;

    float* ws_f = (float*)d_ws;
    int*   ws_i = (int*)d_ws;
    int*   idx  = ws_i + IDX_OFF;
    float* xsq  = ws_f + XSQ_OFF;
    float* esq  = ws_f + ESQ_OFF;
    float* esqh = ws_f + ESQH_OFF;
    int*   hist = ws_i + HIST_OFF;
    float* bkt  = ws_f + BKT_OFF;
    int*   cnt  = ws_i + CNT_OFF;
    int*   flg  = ws_i + FLG_OFF;
    float* cbT  = ws_f + CBT_OFF;
    __half* cbTh = (__half*)(ws_f + CBTH_OFF);

    // x hi fp16 plane lives in d_out (overwritten by quant_k at the end)
    __half* xh = (__half*)d_out;

    hipMemsetAsync((char*)d_ws + (size_t)HIST_OFF * 4, 0,
                   (NUM_EMB + 256 + 1) * sizeof(float), stream);

    prep_all<<<8 + 128 + N_ROWS / 4, 256, 0, stream>>>(x, cb, esq, esqh, cbT, cbTh, xh, xsq);
    argmin_mfma<<<N_ROWS / 64, 256, 0, stream>>>(xh, cbTh, esqh, idx, cnt, flg);
    fallback_k<<<512, 256, 0, stream>>>(x, cb, xsq, esq, cnt, flg, idx);
    quant_k<<<N_ROWS / 4, 256, 0, stream>>>(x, cbT, idx, out, bkt, hist);
    final_k<<<1, 256, 0, stream>>>(bkt, hist, out);
}

// Round 8
// 395.418 us; speedup vs baseline: 1.3094x; 1.0915x over previous
//
#include <hip/hip_runtime.h>
#include <hip/hip_fp16.h>
#include <math.h>

#define EMB_DIM 256
#define NUM_EMB 2048
#define N_ROWS  65536            // 64*32*32
#define N_ELEM  16777216         // N_ROWS * EMB_DIM
#define EPS_GAP 8e-3f            // ~10 sigma of 1-pass ordering error

// ---- workspace layout (in 4-byte elements) ----
#define IDX_OFF    0             // int[65536]
#define XSQ_OFF    65536         // float[65536]
#define ESQ_OFF    131072        // float[2048]  exact ||e||^2 (fallback)
#define ESQH_OFF   133120        // float[2048]  ||eh||^2 (fp16-rounded, main)
#define HIST_OFF   135168        // int[2048]
#define BKT_OFF    137216        // float[256]
#define CNT_OFF    137472        // int[1]
#define FLG_OFF    137473        // int[65536]  compacted flagged-row list
#define FLGB_OFF   204800        // uchar[65536] flagged bitmap (16384 elems)
#define CBT_OFF    262144        // float[2048][256]  (transposed codebook)
#define CBTH_OFF   786432        // f16 [2048][256] hi plane (1 MB)

typedef __attribute__((ext_vector_type(8))) _Float16 half8;
typedef __attribute__((ext_vector_type(4))) float f32x4;
typedef unsigned int u32;

__device__ __forceinline__ void gl_lds16(const void* g, void* l) {
    __builtin_amdgcn_global_load_lds(
        (const __attribute__((address_space(1))) u32*)g,
        (__attribute__((address_space(3))) u32*)l, 16, 0, 0);
}

// ---------- fused prep: esq (blocks 0-7) + cbt transpose (8-135) + x fp16 (136+) ----------
__global__ __launch_bounds__(256) void prep_all(
    const float* __restrict__ x, const float* __restrict__ cb,
    float* __restrict__ esq, float* __restrict__ esqh,
    float* __restrict__ cbT, __half* __restrict__ cbTh,
    __half* __restrict__ xh, float* __restrict__ xsq) {
    __shared__ float lt[64][65];
    const int bid = blockIdx.x;
    const int t = threadIdx.x;
    if (bid < 8) {
        int e = bid * 256 + t;
        float s0 = 0.f, s1 = 0.f, s2 = 0.f, s3 = 0.f;
        float h0 = 0.f, h1 = 0.f, h2 = 0.f, h3 = 0.f;
        for (int d = 0; d < EMB_DIM; d += 4) {
            float c0 = cb[(d + 0) * NUM_EMB + e];
            float c1 = cb[(d + 1) * NUM_EMB + e];
            float c2 = cb[(d + 2) * NUM_EMB + e];
            float c3 = cb[(d + 3) * NUM_EMB + e];
            s0 = fmaf(c0, c0, s0); s1 = fmaf(c1, c1, s1);
            s2 = fmaf(c2, c2, s2); s3 = fmaf(c3, c3, s3);
            float q0 = __half2float(__float2half(c0));
            float q1 = __half2float(__float2half(c1));
            float q2 = __half2float(__float2half(c2));
            float q3 = __half2float(__float2half(c3));
            h0 = fmaf(q0, q0, h0); h1 = fmaf(q1, q1, h1);
            h2 = fmaf(q2, q2, h2); h3 = fmaf(q3, q3, h3);
        }
        esq[e]  = (s0 + s1) + (s2 + s3);
        esqh[e] = (h0 + h1) + (h2 + h3);
    } else if (bid < 136) {
        int b = bid - 8;
        int et = (b & 31) * 64;
        int dt = (b >> 5) * 64;
        #pragma unroll
        for (int p = 0; p < 4; ++p) {
            int d  = p * 16 + (t >> 4);
            int e4 = (t & 15) * 4;
            const float4 v = *(const float4*)&cb[(dt + d) * NUM_EMB + et + e4];
            lt[d][e4] = v.x; lt[d][e4 + 1] = v.y; lt[d][e4 + 2] = v.z; lt[d][e4 + 3] = v.w;
        }
        __syncthreads();
        #pragma unroll
        for (int p = 0; p < 4; ++p) {
            int e  = p * 16 + (t >> 4);
            int d4 = (t & 15) * 4;
            float a[4] = {lt[d4][e], lt[d4 + 1][e], lt[d4 + 2][e], lt[d4 + 3][e]};
            *(float4*)&cbT[(et + e) * EMB_DIM + dt + d4] = make_float4(a[0], a[1], a[2], a[3]);
            unsigned short hb[4];
            #pragma unroll
            for (int i = 0; i < 4; ++i)
                hb[i] = __half_as_ushort(__float2half(a[i]));
            *(ushort4*)&cbTh[(et + e) * EMB_DIM + dt + d4] = make_ushort4(hb[0], hb[1], hb[2], hb[3]);
        }
    } else {
        // x -> fp16 hi plane + ||x||^2; 8 rows/block (2 groups of 4) for more ILP.
        int b = bid - 136;
        #pragma unroll
        for (int gdup = 0; gdup < 2; ++gdup) {
            int row = b * 8 + gdup * 4 + (t >> 6);
            int c = (t & 63) * 4;
            const float4 v = *(const float4*)&x[(size_t)row * EMB_DIM + c];
            float a[4] = {v.x, v.y, v.z, v.w};
            unsigned short hb[4];
            float s = 0.f;
            #pragma unroll
            for (int i = 0; i < 4; ++i) {
                hb[i] = __half_as_ushort(__float2half(a[i]));
                s = fmaf(a[i], a[i], s);
            }
            *(ushort4*)&xh[(size_t)row * EMB_DIM + c] = make_ushort4(hb[0], hb[1], hb[2], hb[3]);
            #pragma unroll
            for (int o = 32; o > 0; o >>= 1) s += __shfl_down(s, o, 64);
            if ((t & 63) == 0) xsq[row] = s;
        }
    }
}

// ---------- main: 1-pass MFMA score + per-row argmin (unchanged pipeline) ----------
#define BUFH 20480   // halfs per buffer: A0 2048 + A1 2048 + B0 8192 + B1 8192 (40 KB)
__global__ __launch_bounds__(256, 2) void argmin_mfma(
    const __half* __restrict__ xh_, const __half* __restrict__ cbh_,
    const float* __restrict__ esqh,
    int* __restrict__ idx_out, int* __restrict__ cnt, int* __restrict__ flg,
    unsigned char* __restrict__ flagged) {

    __shared__ _Float16 ldsbuf[2 * BUFH];          // 80 KB -> 2 blocks/CU
    _Float16* lds = ldsbuf;

    const _Float16* xh  = (const _Float16*)xh_;
    const _Float16* cbh = (const _Float16*)cbh_;

    const int t = threadIdx.x;
    const int w = t >> 6, L = t & 63;
    const int wn = w * 64;
    const int lm = L & 15, lq = L >> 4;
    const int ph = (lm >> 1) & 3;
    const int rowbase = blockIdx.x * 64;

    const int srow = L >> 2;
    const int sq   = (L & 3) ^ ((L >> 3) & 3);

    const _Float16* pa  = xh + (size_t)(rowbase + w * 16 + srow) * EMB_DIM + sq * 8;
    const _Float16* pb0 = cbh + (size_t)(w * 16 + srow) * EMB_DIM + sq * 8;
    const int oA = (w * 16) * 32;
    const int oB = (w * 16) * 32;

    float best[16], b2[16];
    int   bi[16];
    #pragma unroll
    for (int s = 0; s < 16; ++s) { best[s] = 3.4e38f; b2[s] = 3.4e38f; bi[s] = 0; }

    #define STAGE(S_, bb) do {                                                   \
        const int nnt_ = (S_) >> 2;                                              \
        const int km_  = ((S_) & 3) * 64;                                        \
        const _Float16* pb_ = pb0 + (size_t)nnt_ * 256 * EMB_DIM + km_;          \
        gl_lds16(pa + km_,                 (bb) + oA);                           \
        gl_lds16(pa + km_ + 32,            (bb) + 2048 + oA);                    \
        gl_lds16(pb_ +   0 * EMB_DIM,      (bb) + 4096 + oB);                    \
        gl_lds16(pb_ +  64 * EMB_DIM,      (bb) + 4096 + oB + 2048);             \
        gl_lds16(pb_ + 128 * EMB_DIM,      (bb) + 4096 + oB + 4096);             \
        gl_lds16(pb_ + 192 * EMB_DIM,      (bb) + 4096 + oB + 6144);             \
        gl_lds16(pb_ +   0 * EMB_DIM + 32, (bb) + 12288 + oB);                   \
        gl_lds16(pb_ +  64 * EMB_DIM + 32, (bb) + 12288 + oB + 2048);            \
        gl_lds16(pb_ + 128 * EMB_DIM + 32, (bb) + 12288 + oB + 4096);            \
        gl_lds16(pb_ + 192 * EMB_DIM + 32, (bb) + 12288 + oB + 6144);            \
    } while (0)

    STAGE(0, lds);

    for (int nt = 0; nt < 8; ++nt) {
        float eq[4];
        #pragma unroll
        for (int g = 0; g < 4; ++g)
            eq[g] = esqh[nt * 256 + wn + g * 16 + lm];

        f32x4 acc[4][4];
        #pragma unroll
        for (int f = 0; f < 4; ++f)
            #pragma unroll
            for (int g = 0; g < 4; ++g)
                acc[f][g] = (f32x4){0.f, 0.f, 0.f, 0.f};

        for (int mt = 0; mt < 4; ++mt) {
            const int S = nt * 4 + mt;

            __builtin_amdgcn_sched_barrier(0);
            asm volatile("s_waitcnt vmcnt(0)" ::: "memory");
            __builtin_amdgcn_s_barrier();
            __builtin_amdgcn_sched_barrier(0);

            if (S < 31)
                STAGE(S + 1, lds + ((S + 1) & 1) * BUFH);

            const _Float16* bb = lds + (S & 1) * BUFH;

            half8 ah[2][4], bh[2][4];
            #pragma unroll
            for (int h = 0; h < 2; ++h)
                #pragma unroll
                for (int f = 0; f < 4; ++f)
                    ah[h][f] = *(const half8*)&bb[h * 2048 + (f * 16 + lm) * 32 + ((lq ^ ph) * 8)];
            #pragma unroll
            for (int h = 0; h < 2; ++h)
                #pragma unroll
                for (int g = 0; g < 4; ++g)
                    bh[h][g] = *(const half8*)&bb[4096 + h * 8192 + (wn + g * 16 + lm) * 32 + ((lq ^ ph) * 8)];

            asm volatile("s_waitcnt lgkmcnt(0)" ::: "memory");
            __builtin_amdgcn_sched_barrier(0);
            __builtin_amdgcn_s_barrier();
            __builtin_amdgcn_sched_barrier(0);

            __builtin_amdgcn_s_setprio(1);
            #pragma unroll
            for (int h = 0; h < 2; ++h)
                #pragma unroll
                for (int f = 0; f < 4; ++f)
                    #pragma unroll
                    for (int g = 0; g < 4; ++g)
                        acc[f][g] = __builtin_amdgcn_mfma_f32_16x16x32_f16(ah[h][f], bh[h][g], acc[f][g], 0, 0, 0);
            __builtin_amdgcn_s_setprio(0);
        }

        #pragma unroll
        for (int g = 0; g < 4; ++g) {
            int col = nt * 256 + wn + g * 16 + lm;
            #pragma unroll
            for (int f = 0; f < 4; ++f)
                #pragma unroll
                for (int r = 0; r < 4; ++r) {
                    int s = f * 4 + r;
                    float v = fmaf(-2.0f, acc[f][g][r], eq[g]);
                    float bo = best[s];
                    b2[s]   = fminf(b2[s], fmaxf(bo, v));
                    best[s] = fminf(bo, v);
                    bi[s]   = (v < bo) ? col : bi[s];
                }
        }
    }
    #undef STAGE

    // block-level reduce: 64 candidates per row; pitch 65 -> conflict-free column scan
    __syncthreads();
    float* smemf = (float*)ldsbuf;
    float* rd = smemf;                  // [64][65]
    int*   ri = (int*)(smemf + 4160);
    float* r2 = smemf + 8320;
    #pragma unroll
    for (int f = 0; f < 4; ++f)
        #pragma unroll
        for (int r = 0; r < 4; ++r) {
            int row = f * 16 + lq * 4 + r;
            int c = w * 16 + lm;
            rd[row * 65 + c] = best[f * 4 + r];
            ri[row * 65 + c] = bi[f * 4 + r];
            r2[row * 65 + c] = b2[f * 4 + r];
        }
    __syncthreads();
    if (t < 64) {
        int row = t;
        float g1 = rd[row * 65]; int gi = ri[row * 65]; float g2 = r2[row * 65];
        for (int c = 1; c < 64; ++c) {
            float d = rd[row * 65 + c]; int ic = ri[row * 65 + c]; float d2 = r2[row * 65 + c];
            if (d < g1 || (d == g1 && ic < gi)) { g2 = fminf(g1, d2); g1 = d; gi = ic; }
            else g2 = fminf(g2, d);
        }
        idx_out[rowbase + row] = gi;
        if (g2 - g1 < EPS_GAP) {       // near-tie: route to exact fp32 fallback
            int p = atomicAdd(cnt, 1);
            flg[p] = rowbase + row;
            flagged[rowbase + row] = 1;
        }
    }
}

// ---------- merged: exact recheck+quant for flagged rows, then quant for the rest ----------
// Phase 1: each block rechecks its flagged 4-row groups (distance math verbatim from the
// verified fallback) and quantizes those rows immediately with the FINAL index (x row is
// already in LDS). Phase 2: grid-stride quant of all non-flagged rows (body verbatim from
// the verified quant_k -> bit-identical per row). Every row quantized exactly once.
__global__ __launch_bounds__(256) void fallback_quant_k(
    const float* __restrict__ x, const float* __restrict__ cb,
    const float* __restrict__ cbT,
    const float* __restrict__ xsq, const float* __restrict__ esq,
    const int* __restrict__ cnt, const int* __restrict__ rows,
    const unsigned char* __restrict__ flagged,
    int* __restrict__ idx, float* __restrict__ out,
    float* __restrict__ bkt, int* __restrict__ hist) {
    __shared__ float xr[4][256];
    __shared__ float sd[4][256];
    __shared__ int   si[4][256];
    const int t = threadIdx.x;
    const int w = t >> 6, L = t & 63;
    int n = *cnt;

    // ---- phase 1: flagged rows ----
    for (int base = blockIdx.x * 4; base < n; base += gridDim.x * 4) {
        int rws[4];
        #pragma unroll
        for (int r = 0; r < 4; ++r) {
            int fi = base + r;
            rws[r] = rows[(fi < n) ? fi : (n - 1)];   // pad by repeating last (loads only)
        }
        __syncthreads();   // WAR vs previous group's xr/sd/si use
        #pragma unroll
        for (int r = 0; r < 4; ++r) xr[r][t] = x[(size_t)rws[r] * EMB_DIM + t];
        __syncthreads();

        float bd[4]; int bidx[4];
        #pragma unroll
        for (int r = 0; r < 4; ++r) { bd[r] = 3.4e38f; bidx[r] = 0x7fffffff; }

        for (int j = 0; j < 8; ++j) {
            int e = j * 256 + t;
            float s0[4], s1[4], s2[4], s3[4];
            #pragma unroll
            for (int r = 0; r < 4; ++r) { s0[r] = 0.f; s1[r] = 0.f; s2[r] = 0.f; s3[r] = 0.f; }
            for (int d = 0; d < EMB_DIM; d += 4) {
                float c0 = cb[(size_t)(d + 0) * NUM_EMB + e];
                float c1 = cb[(size_t)(d + 1) * NUM_EMB + e];
                float c2 = cb[(size_t)(d + 2) * NUM_EMB + e];
                float c3 = cb[(size_t)(d + 3) * NUM_EMB + e];
                #pragma unroll
                for (int r = 0; r < 4; ++r) {
                    const float4 xv = *(const float4*)&xr[r][d];
                    s0[r] = fmaf(xv.x, c0, s0[r]);
                    s1[r] = fmaf(xv.y, c1, s1[r]);
                    s2[r] = fmaf(xv.z, c2, s2[r]);
                    s3[r] = fmaf(xv.w, c3, s3[r]);
                }
            }
            float eqv = esq[e];
            #pragma unroll
            for (int r = 0; r < 4; ++r) {
                float sim = (s0[r] + s1[r]) + (s2[r] + s3[r]);
                float dd = (xsq[rws[r]] + eqv) - 2.0f * sim;
                if (dd < bd[r]) { bd[r] = dd; bidx[r] = e; }   // e ascends per thread
            }
        }
        #pragma unroll
        for (int r = 0; r < 4; ++r) { sd[r][t] = bd[r]; si[r][t] = bidx[r]; }
        __syncthreads();
        for (int r = 0; r < 4; ++r) {
            for (int stp = 128; stp > 0; stp >>= 1) {
                if (t < stp) {
                    if (sd[r][t + stp] < sd[r][t] ||
                        (sd[r][t + stp] == sd[r][t] && si[r][t + stp] < si[r][t])) {
                        sd[r][t] = sd[r][t + stp]; si[r][t] = si[r][t + stp];
                    }
                }
                __syncthreads();
            }
        }
        // post: wave w owns slot w — write final idx + quantize this row now
        if (base + w < n) {
            int rowg = rws[w];
            int e = si[w][0];
            if (L == 0) idx[rowg] = e;
            int c = L * 4;
            const float4 q  = *(const float4*)&cbT[(size_t)e * EMB_DIM + c];
            const float4 xv = *(const float4*)&xr[w][c];
            float4 o;
            o.x = xv.x + (q.x - xv.x); o.y = xv.y + (q.y - xv.y);
            o.z = xv.z + (q.z - xv.z); o.w = xv.w + (q.w - xv.w);
            *(float4*)&out[(size_t)rowg * EMB_DIM + c] = o;
            float dx = xv.x - q.x, dy = xv.y - q.y, dz = xv.z - q.z, dw = xv.w - q.w;
            float val = fmaf(dx, dx, 0.f);
            val = fmaf(dy, dy, val);
            val = fmaf(dz, dz, val);
            val = fmaf(dw, dw, val);
            #pragma unroll
            for (int o2 = 32; o2 > 0; o2 >>= 1) val += __shfl_down(val, o2, 64);
            if (L == 0) {
                atomicAdd(&bkt[rowg & 255], val);
                atomicAdd(&hist[e], 1);
            }
        }
    }

    // ---- phase 2: non-flagged rows, grid-stride (verbatim quant_k body per row) ----
    for (int qb = blockIdx.x; qb < N_ROWS / 4; qb += gridDim.x) {
        int row = qb * 4 + w;
        if (flagged[row]) continue;                  // wave-uniform
        int e = idx[row];
        int c = L * 4;
        const float4 q  = *(const float4*)&cbT[(size_t)e * EMB_DIM + c];
        const float4 xv = *(const float4*)&x[(size_t)row * EMB_DIM + c];
        float4 o;
        o.x = xv.x + (q.x - xv.x); o.y = xv.y + (q.y - xv.y);
        o.z = xv.z + (q.z - xv.z); o.w = xv.w + (q.w - xv.w);
        *(float4*)&out[(size_t)row * EMB_DIM + c] = o;
        float dx = xv.x - q.x, dy = xv.y - q.y, dz = xv.z - q.z, dw = xv.w - q.w;
        float val = fmaf(dx, dx, 0.f);
        val = fmaf(dy, dy, val);
        val = fmaf(dz, dz, val);
        val = fmaf(dw, dw, val);
        #pragma unroll
        for (int o2 = 32; o2 > 0; o2 >>= 1) val += __shfl_down(val, o2, 64);
        if (L == 0) {
            atomicAdd(&bkt[row & 255], val);
            atomicAdd(&hist[e], 1);
        }
    }
}

// ---------- finalize loss + perplexity ----------
__global__ __launch_bounds__(256) void final_k(const float* __restrict__ bkt,
                                               const int* __restrict__ hist,
                                               float* __restrict__ out) {
    int t = threadIdx.x;
    double ls = (double)bkt[t];
    double ps = 0.0;
    for (int i = t; i < NUM_EMB; i += 256) {
        double p = (double)hist[i] / (double)N_ROWS;
        ps += p * log(p + 1e-10);
    }
    __shared__ double sdd[256], spp[256];
    sdd[t] = ls; spp[t] = ps;
    __syncthreads();
    for (int s = 128; s > 0; s >>= 1) {
        if (t < s) { sdd[t] += sdd[t + s]; spp[t] += spp[t + s]; }
        __syncthreads();
    }
    if (t == 0) {
        out[N_ELEM + 0] = (float)(1.25 * sdd[0] / (double)N_ELEM);
        out[N_ELEM + 1] = (float)exp(-spp[0]);
    }
}

extern "C" void kernel_launch(void* const* d_in, const int* in_sizes, int n_in,
                              void* d_out, int out_size, void* d_ws, size_t ws_size,
                              hipStream_t stream) {
    const float* x  = (const float*)d_in[0];
    const float* cb = (const float*)d_in[1];
    float* out = (float*)d_out;

    float* ws_f = (float*)d_ws;
    int*   ws_i = (int*)d_ws;
    int*   idx  = ws_i + IDX_OFF;
    float* xsq  = ws_f + XSQ_OFF;
    float* esq  = ws_f + ESQ_OFF;
    float* esqh = ws_f + ESQH_OFF;
    int*   hist = ws_i + HIST_OFF;
    float* bkt  = ws_f + BKT_OFF;
    int*   cnt  = ws_i + CNT_OFF;
    int*   flg  = ws_i + FLG_OFF;
    unsigned char* flagged = (unsigned char*)(ws_i + FLGB_OFF);
    float* cbT  = ws_f + CBT_OFF;
    __half* cbTh = (__half*)(ws_f + CBTH_OFF);

    // x hi fp16 plane lives in d_out (read only by argmin; overwritten afterwards)
    __half* xh = (__half*)d_out;

    hipMemsetAsync((char*)d_ws + (size_t)HIST_OFF * 4, 0,
                   (NUM_EMB + 256 + 1) * sizeof(float), stream);
    hipMemsetAsync((char*)d_ws + (size_t)FLGB_OFF * 4, 0, N_ROWS, stream);

    prep_all<<<8 + 128 + N_ROWS / 8, 256, 0, stream>>>(x, cb, esq, esqh, cbT, cbTh, xh, xsq);
    argmin_mfma<<<N_ROWS / 64, 256, 0, stream>>>(xh, cbTh, esqh, idx, cnt, flg, flagged);
    fallback_quant_k<<<512, 256, 0, stream>>>(x, cb, cbT, xsq, esq, cnt, flg, flagged,
                                              idx, out, bkt, hist);
    final_k<<<1, 256, 0, stream>>>(bkt, hist, out);
}

// Round 9
// 392.780 us; speedup vs baseline: 1.3182x; 1.0067x over previous
//
#include <hip/hip_runtime.h>
#include <hip/hip_fp16.h>
#include <math.h>

#define EMB_DIM 256
#define NUM_EMB 2048
#define N_ROWS  65536            // 64*32*32
#define N_ELEM  16777216         // N_ROWS * EMB_DIM
#define EPS_GAP 8e-3f            // ~10 sigma of 1-pass ordering error

// ---- workspace layout (in 4-byte elements) ----
#define IDX_OFF    0             // int[65536]
#define XSQ_OFF    65536         // float[65536]
#define ESQ_OFF    131072        // float[2048]  exact ||e||^2 (fallback)
#define ESQH_OFF   133120        // float[2048]  ||eh||^2 (fp16-rounded, main)
#define HIST_OFF   135168        // int[2048]
#define BKT_OFF    137216        // float[256]
#define CNT_OFF    137472        // int[1]
#define FLG_OFF    137473        // int[65536]  compacted flagged-row list
#define FLGB_OFF   204800        // uchar[65536] flagged bitmap (16384 elems)
#define CBT_OFF    262144        // float[2048][256]  (transposed codebook)
#define CBTH_OFF   786432        // f16 [2048][256] hi plane (1 MB)

typedef __attribute__((ext_vector_type(8))) _Float16 half8;
typedef __attribute__((ext_vector_type(4))) float f32x4;
typedef unsigned int u32;

__device__ __forceinline__ void gl_lds16(const void* g, void* l) {
    __builtin_amdgcn_global_load_lds(
        (const __attribute__((address_space(1))) u32*)g,
        (__attribute__((address_space(3))) u32*)l, 16, 0, 0);
}

// ---------- fused prep: esq (blocks 0-7) + cbt transpose (8-135) + x fp16 (136+) ----------
__global__ __launch_bounds__(256) void prep_all(
    const float* __restrict__ x, const float* __restrict__ cb,
    float* __restrict__ esq, float* __restrict__ esqh,
    float* __restrict__ cbT, __half* __restrict__ cbTh,
    __half* __restrict__ xh, float* __restrict__ xsq) {
    __shared__ float lt[64][65];
    const int bid = blockIdx.x;
    const int t = threadIdx.x;
    if (bid < 8) {
        int e = bid * 256 + t;
        float s0 = 0.f, s1 = 0.f, s2 = 0.f, s3 = 0.f;
        float h0 = 0.f, h1 = 0.f, h2 = 0.f, h3 = 0.f;
        for (int d = 0; d < EMB_DIM; d += 4) {
            float c0 = cb[(d + 0) * NUM_EMB + e];
            float c1 = cb[(d + 1) * NUM_EMB + e];
            float c2 = cb[(d + 2) * NUM_EMB + e];
            float c3 = cb[(d + 3) * NUM_EMB + e];
            s0 = fmaf(c0, c0, s0); s1 = fmaf(c1, c1, s1);
            s2 = fmaf(c2, c2, s2); s3 = fmaf(c3, c3, s3);
            float q0 = __half2float(__float2half(c0));
            float q1 = __half2float(__float2half(c1));
            float q2 = __half2float(__float2half(c2));
            float q3 = __half2float(__float2half(c3));
            h0 = fmaf(q0, q0, h0); h1 = fmaf(q1, q1, h1);
            h2 = fmaf(q2, q2, h2); h3 = fmaf(q3, q3, h3);
        }
        esq[e]  = (s0 + s1) + (s2 + s3);
        esqh[e] = (h0 + h1) + (h2 + h3);
    } else if (bid < 136) {
        int b = bid - 8;
        int et = (b & 31) * 64;
        int dt = (b >> 5) * 64;
        #pragma unroll
        for (int p = 0; p < 4; ++p) {
            int d  = p * 16 + (t >> 4);
            int e4 = (t & 15) * 4;
            const float4 v = *(const float4*)&cb[(dt + d) * NUM_EMB + et + e4];
            lt[d][e4] = v.x; lt[d][e4 + 1] = v.y; lt[d][e4 + 2] = v.z; lt[d][e4 + 3] = v.w;
        }
        __syncthreads();
        #pragma unroll
        for (int p = 0; p < 4; ++p) {
            int e  = p * 16 + (t >> 4);
            int d4 = (t & 15) * 4;
            float a[4] = {lt[d4][e], lt[d4 + 1][e], lt[d4 + 2][e], lt[d4 + 3][e]};
            *(float4*)&cbT[(et + e) * EMB_DIM + dt + d4] = make_float4(a[0], a[1], a[2], a[3]);
            unsigned short hb[4];
            #pragma unroll
            for (int i = 0; i < 4; ++i)
                hb[i] = __half_as_ushort(__float2half(a[i]));
            *(ushort4*)&cbTh[(et + e) * EMB_DIM + dt + d4] = make_ushort4(hb[0], hb[1], hb[2], hb[3]);
        }
    } else {
        // x -> fp16 hi plane + ||x||^2; 8 rows/block (2 groups of 4) for more ILP.
        int b = bid - 136;
        #pragma unroll
        for (int gdup = 0; gdup < 2; ++gdup) {
            int row = b * 8 + gdup * 4 + (t >> 6);
            int c = (t & 63) * 4;
            const float4 v = *(const float4*)&x[(size_t)row * EMB_DIM + c];
            float a[4] = {v.x, v.y, v.z, v.w};
            unsigned short hb[4];
            float s = 0.f;
            #pragma unroll
            for (int i = 0; i < 4; ++i) {
                hb[i] = __half_as_ushort(__float2half(a[i]));
                s = fmaf(a[i], a[i], s);
            }
            *(ushort4*)&xh[(size_t)row * EMB_DIM + c] = make_ushort4(hb[0], hb[1], hb[2], hb[3]);
            #pragma unroll
            for (int o = 32; o > 0; o >>= 1) s += __shfl_down(s, o, 64);
            if ((t & 63) == 0) xsq[row] = s;
        }
    }
}

// ---------- main: 1-pass MFMA score + per-row argmin (unchanged pipeline) ----------
#define BUFH 20480   // halfs per buffer: A0 2048 + A1 2048 + B0 8192 + B1 8192 (40 KB)
__global__ __launch_bounds__(256, 2) void argmin_mfma(
    const __half* __restrict__ xh_, const __half* __restrict__ cbh_,
    const float* __restrict__ esqh,
    int* __restrict__ idx_out, int* __restrict__ cnt, int* __restrict__ flg,
    unsigned char* __restrict__ flagged) {

    __shared__ _Float16 ldsbuf[2 * BUFH];          // 80 KB -> 2 blocks/CU
    _Float16* lds = ldsbuf;

    const _Float16* xh  = (const _Float16*)xh_;
    const _Float16* cbh = (const _Float16*)cbh_;

    const int t = threadIdx.x;
    const int w = t >> 6, L = t & 63;
    const int wn = w * 64;
    const int lm = L & 15, lq = L >> 4;
    const int ph = (lm >> 1) & 3;
    const int rowbase = blockIdx.x * 64;

    const int srow = L >> 2;
    const int sq   = (L & 3) ^ ((L >> 3) & 3);

    const _Float16* pa  = xh + (size_t)(rowbase + w * 16 + srow) * EMB_DIM + sq * 8;
    const _Float16* pb0 = cbh + (size_t)(w * 16 + srow) * EMB_DIM + sq * 8;
    const int oA = (w * 16) * 32;
    const int oB = (w * 16) * 32;

    float best[16], b2[16];
    int   bi[16];
    #pragma unroll
    for (int s = 0; s < 16; ++s) { best[s] = 3.4e38f; b2[s] = 3.4e38f; bi[s] = 0; }

    #define STAGE(S_, bb) do {                                                   \
        const int nnt_ = (S_) >> 2;                                              \
        const int km_  = ((S_) & 3) * 64;                                        \
        const _Float16* pb_ = pb0 + (size_t)nnt_ * 256 * EMB_DIM + km_;          \
        gl_lds16(pa + km_,                 (bb) + oA);                           \
        gl_lds16(pa + km_ + 32,            (bb) + 2048 + oA);                    \
        gl_lds16(pb_ +   0 * EMB_DIM,      (bb) + 4096 + oB);                    \
        gl_lds16(pb_ +  64 * EMB_DIM,      (bb) + 4096 + oB + 2048);             \
        gl_lds16(pb_ + 128 * EMB_DIM,      (bb) + 4096 + oB + 4096);             \
        gl_lds16(pb_ + 192 * EMB_DIM,      (bb) + 4096 + oB + 6144);             \
        gl_lds16(pb_ +   0 * EMB_DIM + 32, (bb) + 12288 + oB);                   \
        gl_lds16(pb_ +  64 * EMB_DIM + 32, (bb) + 12288 + oB + 2048);            \
        gl_lds16(pb_ + 128 * EMB_DIM + 32, (bb) + 12288 + oB + 4096);            \
        gl_lds16(pb_ + 192 * EMB_DIM + 32, (bb) + 12288 + oB + 6144);            \
    } while (0)

    STAGE(0, lds);

    for (int nt = 0; nt < 8; ++nt) {
        float eq[4];
        #pragma unroll
        for (int g = 0; g < 4; ++g)
            eq[g] = esqh[nt * 256 + wn + g * 16 + lm];

        f32x4 acc[4][4];
        #pragma unroll
        for (int f = 0; f < 4; ++f)
            #pragma unroll
            for (int g = 0; g < 4; ++g)
                acc[f][g] = (f32x4){0.f, 0.f, 0.f, 0.f};

        for (int mt = 0; mt < 4; ++mt) {
            const int S = nt * 4 + mt;

            __builtin_amdgcn_sched_barrier(0);
            asm volatile("s_waitcnt vmcnt(0)" ::: "memory");
            __builtin_amdgcn_s_barrier();
            __builtin_amdgcn_sched_barrier(0);

            if (S < 31)
                STAGE(S + 1, lds + ((S + 1) & 1) * BUFH);

            const _Float16* bb = lds + (S & 1) * BUFH;

            half8 ah[2][4], bh[2][4];
            #pragma unroll
            for (int h = 0; h < 2; ++h)
                #pragma unroll
                for (int f = 0; f < 4; ++f)
                    ah[h][f] = *(const half8*)&bb[h * 2048 + (f * 16 + lm) * 32 + ((lq ^ ph) * 8)];
            #pragma unroll
            for (int h = 0; h < 2; ++h)
                #pragma unroll
                for (int g = 0; g < 4; ++g)
                    bh[h][g] = *(const half8*)&bb[4096 + h * 8192 + (wn + g * 16 + lm) * 32 + ((lq ^ ph) * 8)];

            asm volatile("s_waitcnt lgkmcnt(0)" ::: "memory");
            __builtin_amdgcn_sched_barrier(0);
            __builtin_amdgcn_s_barrier();
            __builtin_amdgcn_sched_barrier(0);

            __builtin_amdgcn_s_setprio(1);
            #pragma unroll
            for (int h = 0; h < 2; ++h)
                #pragma unroll
                for (int f = 0; f < 4; ++f)
                    #pragma unroll
                    for (int g = 0; g < 4; ++g)
                        acc[f][g] = __builtin_amdgcn_mfma_f32_16x16x32_f16(ah[h][f], bh[h][g], acc[f][g], 0, 0, 0);
            __builtin_amdgcn_s_setprio(0);
        }

        #pragma unroll
        for (int g = 0; g < 4; ++g) {
            int col = nt * 256 + wn + g * 16 + lm;
            #pragma unroll
            for (int f = 0; f < 4; ++f)
                #pragma unroll
                for (int r = 0; r < 4; ++r) {
                    int s = f * 4 + r;
                    float v = fmaf(-2.0f, acc[f][g][r], eq[g]);
                    float bo = best[s];
                    b2[s]   = fminf(b2[s], fmaxf(bo, v));
                    best[s] = fminf(bo, v);
                    bi[s]   = (v < bo) ? col : bi[s];
                }
        }
    }
    #undef STAGE

    // block-level reduce: 64 candidates per row; pitch 65 -> conflict-free column scan
    __syncthreads();
    float* smemf = (float*)ldsbuf;
    float* rd = smemf;                  // [64][65]
    int*   ri = (int*)(smemf + 4160);
    float* r2 = smemf + 8320;
    #pragma unroll
    for (int f = 0; f < 4; ++f)
        #pragma unroll
        for (int r = 0; r < 4; ++r) {
            int row = f * 16 + lq * 4 + r;
            int c = w * 16 + lm;
            rd[row * 65 + c] = best[f * 4 + r];
            ri[row * 65 + c] = bi[f * 4 + r];
            r2[row * 65 + c] = b2[f * 4 + r];
        }
    __syncthreads();
    if (t < 64) {
        int row = t;
        float g1 = rd[row * 65]; int gi = ri[row * 65]; float g2 = r2[row * 65];
        for (int c = 1; c < 64; ++c) {
            float d = rd[row * 65 + c]; int ic = ri[row * 65 + c]; float d2 = r2[row * 65 + c];
            if (d < g1 || (d == g1 && ic < gi)) { g2 = fminf(g1, d2); g1 = d; gi = ic; }
            else g2 = fminf(g2, d);
        }
        idx_out[rowbase + row] = gi;
        if (g2 - g1 < EPS_GAP) {       // near-tie: route to exact fp32 fallback
            int p = atomicAdd(cnt, 1);
            flg[p] = rowbase + row;
            flagged[rowbase + row] = 1;
        }
    }
}

// ---------- merged: exact recheck+quant for flagged rows, then quant for the rest ----------
// Phase 1: blocks grid-stride over flagged 4-row groups (distance math verbatim from the
// verified fallback) and quantize those rows immediately with the FINAL index. Phase 2:
// one 4-row group per block (verbatim quant_k body per row -> bit-identical).
// Grid = 16384 (round-8 lesson: 512 blocks under-parallelized the latency-bound phase 2
// by 32x -> 178 us at 9% HBM; phase-1 total work is grid-size-invariant).
__global__ __launch_bounds__(256) void fallback_quant_k(
    const float* __restrict__ x, const float* __restrict__ cb,
    const float* __restrict__ cbT,
    const float* __restrict__ xsq, const float* __restrict__ esq,
    const int* __restrict__ cnt, const int* __restrict__ rows,
    const unsigned char* __restrict__ flagged,
    int* __restrict__ idx, float* __restrict__ out,
    float* __restrict__ bkt, int* __restrict__ hist) {
    __shared__ float xr[4][256];
    __shared__ float sd[4][256];
    __shared__ int   si[4][256];
    const int t = threadIdx.x;
    const int w = t >> 6, L = t & 63;
    int n = *cnt;

    // ---- phase 1: flagged rows ----
    for (int base = blockIdx.x * 4; base < n; base += gridDim.x * 4) {
        int rws[4];
        #pragma unroll
        for (int r = 0; r < 4; ++r) {
            int fi = base + r;
            rws[r] = rows[(fi < n) ? fi : (n - 1)];   // pad by repeating last (loads only)
        }
        __syncthreads();   // WAR vs previous group's xr/sd/si use
        #pragma unroll
        for (int r = 0; r < 4; ++r) xr[r][t] = x[(size_t)rws[r] * EMB_DIM + t];
        __syncthreads();

        float bd[4]; int bidx[4];
        #pragma unroll
        for (int r = 0; r < 4; ++r) { bd[r] = 3.4e38f; bidx[r] = 0x7fffffff; }

        for (int j = 0; j < 8; ++j) {
            int e = j * 256 + t;
            float s0[4], s1[4], s2[4], s3[4];
            #pragma unroll
            for (int r = 0; r < 4; ++r) { s0[r] = 0.f; s1[r] = 0.f; s2[r] = 0.f; s3[r] = 0.f; }
            for (int d = 0; d < EMB_DIM; d += 4) {
                float c0 = cb[(size_t)(d + 0) * NUM_EMB + e];
                float c1 = cb[(size_t)(d + 1) * NUM_EMB + e];
                float c2 = cb[(size_t)(d + 2) * NUM_EMB + e];
                float c3 = cb[(size_t)(d + 3) * NUM_EMB + e];
                #pragma unroll
                for (int r = 0; r < 4; ++r) {
                    const float4 xv = *(const float4*)&xr[r][d];
                    s0[r] = fmaf(xv.x, c0, s0[r]);
                    s1[r] = fmaf(xv.y, c1, s1[r]);
                    s2[r] = fmaf(xv.z, c2, s2[r]);
                    s3[r] = fmaf(xv.w, c3, s3[r]);
                }
            }
            float eqv = esq[e];
            #pragma unroll
            for (int r = 0; r < 4; ++r) {
                float sim = (s0[r] + s1[r]) + (s2[r] + s3[r]);
                float dd = (xsq[rws[r]] + eqv) - 2.0f * sim;
                if (dd < bd[r]) { bd[r] = dd; bidx[r] = e; }   // e ascends per thread
            }
        }
        #pragma unroll
        for (int r = 0; r < 4; ++r) { sd[r][t] = bd[r]; si[r][t] = bidx[r]; }
        __syncthreads();
        for (int r = 0; r < 4; ++r) {
            for (int stp = 128; stp > 0; stp >>= 1) {
                if (t < stp) {
                    if (sd[r][t + stp] < sd[r][t] ||
                        (sd[r][t + stp] == sd[r][t] && si[r][t + stp] < si[r][t])) {
                        sd[r][t] = sd[r][t + stp]; si[r][t] = si[r][t + stp];
                    }
                }
                __syncthreads();
            }
        }
        // post: wave w owns slot w — write final idx + quantize this row now
        if (base + w < n) {
            int rowg = rws[w];
            int e = si[w][0];
            if (L == 0) idx[rowg] = e;
            int c = L * 4;
            const float4 q  = *(const float4*)&cbT[(size_t)e * EMB_DIM + c];
            const float4 xv = *(const float4*)&xr[w][c];
            float4 o;
            o.x = xv.x + (q.x - xv.x); o.y = xv.y + (q.y - xv.y);
            o.z = xv.z + (q.z - xv.z); o.w = xv.w + (q.w - xv.w);
            *(float4*)&out[(size_t)rowg * EMB_DIM + c] = o;
            float dx = xv.x - q.x, dy = xv.y - q.y, dz = xv.z - q.z, dw = xv.w - q.w;
            float val = fmaf(dx, dx, 0.f);
            val = fmaf(dy, dy, val);
            val = fmaf(dz, dz, val);
            val = fmaf(dw, dw, val);
            #pragma unroll
            for (int o2 = 32; o2 > 0; o2 >>= 1) val += __shfl_down(val, o2, 64);
            if (L == 0) {
                atomicAdd(&bkt[rowg & 255], val);
                atomicAdd(&hist[e], 1);
            }
        }
    }

    // ---- phase 2: non-flagged rows (verbatim quant_k body per row) ----
    for (int qb = blockIdx.x; qb < N_ROWS / 4; qb += gridDim.x) {
        int row = qb * 4 + w;
        if (flagged[row]) continue;                  // wave-uniform
        int e = idx[row];
        int c = L * 4;
        const float4 q  = *(const float4*)&cbT[(size_t)e * EMB_DIM + c];
        const float4 xv = *(const float4*)&x[(size_t)row * EMB_DIM + c];
        float4 o;
        o.x = xv.x + (q.x - xv.x); o.y = xv.y + (q.y - xv.y);
        o.z = xv.z + (q.z - xv.z); o.w = xv.w + (q.w - xv.w);
        *(float4*)&out[(size_t)row * EMB_DIM + c] = o;
        float dx = xv.x - q.x, dy = xv.y - q.y, dz = xv.z - q.z, dw = xv.w - q.w;
        float val = fmaf(dx, dx, 0.f);
        val = fmaf(dy, dy, val);
        val = fmaf(dz, dz, val);
        val = fmaf(dw, dw, val);
        #pragma unroll
        for (int o2 = 32; o2 > 0; o2 >>= 1) val += __shfl_down(val, o2, 64);
        if (L == 0) {
            atomicAdd(&bkt[row & 255], val);
            atomicAdd(&hist[e], 1);
        }
    }
}

// ---------- finalize loss + perplexity ----------
__global__ __launch_bounds__(256) void final_k(const float* __restrict__ bkt,
                                               const int* __restrict__ hist,
                                               float* __restrict__ out) {
    int t = threadIdx.x;
    double ls = (double)bkt[t];
    double ps = 0.0;
    for (int i = t; i < NUM_EMB; i += 256) {
        double p = (double)hist[i] / (double)N_ROWS;
        ps += p * log(p + 1e-10);
    }
    __shared__ double sdd[256], spp[256];
    sdd[t] = ls; spp[t] = ps;
    __syncthreads();
    for (int s = 128; s > 0; s >>= 1) {
        if (t < s) { sdd[t] += sdd[t + s]; spp[t] += spp[t + s]; }
        __syncthreads();
    }
    if (t == 0) {
        out[N_ELEM + 0] = (float)(1.25 * sdd[0] / (double)N_ELEM);
        out[N_ELEM + 1] = (float)exp(-spp[0]);
    }
}

extern "C" void kernel_launch(void* const* d_in, const int* in_sizes, int n_in,
                              void* d_out, int out_size, void* d_ws, size_t ws_size,
                              hipStream_t stream) {
    const float* x  = (const float*)d_in[0];
    const float* cb = (const float*)d_in[1];
    float* out = (float*)d_out;

    float* ws_f = (float*)d_ws;
    int*   ws_i = (int*)d_ws;
    int*   idx  = ws_i + IDX_OFF;
    float* xsq  = ws_f + XSQ_OFF;
    float* esq  = ws_f + ESQ_OFF;
    float* esqh = ws_f + ESQH_OFF;
    int*   hist = ws_i + HIST_OFF;
    float* bkt  = ws_f + BKT_OFF;
    int*   cnt  = ws_i + CNT_OFF;
    int*   flg  = ws_i + FLG_OFF;
    unsigned char* flagged = (unsigned char*)(ws_i + FLGB_OFF);
    float* cbT  = ws_f + CBT_OFF;
    __half* cbTh = (__half*)(ws_f + CBTH_OFF);

    // x hi fp16 plane lives in d_out (read only by argmin; overwritten afterwards)
    __half* xh = (__half*)d_out;

    hipMemsetAsync((char*)d_ws + (size_t)HIST_OFF * 4, 0,
                   (NUM_EMB + 256 + 1) * sizeof(float), stream);
    hipMemsetAsync((char*)d_ws + (size_t)FLGB_OFF * 4, 0, N_ROWS, stream);

    prep_all<<<8 + 128 + N_ROWS / 8, 256, 0, stream>>>(x, cb, esq, esqh, cbT, cbTh, xh, xsq);
    argmin_mfma<<<N_ROWS / 64, 256, 0, stream>>>(xh, cbTh, esqh, idx, cnt, flg, flagged);
    fallback_quant_k<<<16384, 256, 0, stream>>>(x, cb, cbT, xsq, esq, cnt, flg, flagged,
                                                idx, out, bkt, hist);
    final_k<<<1, 256, 0, stream>>>(bkt, hist, out);
}